// Round 1
// baseline (2285.580 us; speedup 1.0000x reference)
//
#include <hip/hip_runtime.h>
#include <hip/hip_bf16.h>

#define NB 8
#define NP 1024
#define NPTS (NB * NP)
#define KNN 20

static __device__ __forceinline__ unsigned long long umin64(unsigned long long a,
                                                            unsigned long long b) {
    return a < b ? a : b;
}

// ---------------- squared norms ----------------
template <int C>
__global__ __launch_bounds__(256) void sqnorm_kernel(const float* __restrict__ x,
                                                     float* __restrict__ sqn) {
    int p = blockIdx.x * 256 + threadIdx.x;
    if (p < NPTS) {
        const float* xp = x + (size_t)p * C;
        float s = 0.f;
        for (int c = 0; c < C; ++c) s += xp[c] * xp[c];
        sqn[p] = s;
    }
}

// ---------------- kNN (top-20 smallest distance, tie -> lowest index) ----------------
template <int C>
__global__ __launch_bounds__(256) void knn_kernel(const float* __restrict__ x,
                                                  const float* __restrict__ sqn,
                                                  int* __restrict__ idx) {
    const int p = blockIdx.x;          // global point id
    const int base = (p >> 10) << 10;  // cloud start
    const int tid = threadIdx.x;

    __shared__ float dist[NP];
    __shared__ float xi[C];
    __shared__ unsigned long long rkey[256];

    for (int c = tid; c < C; c += 256) xi[c] = x[(size_t)p * C + c];
    __syncthreads();

    const float sqp = sqn[p];
    for (int q = tid; q < NP; q += 256) {
        const float* xq = x + (size_t)(base + q) * C;
        float dot = 0.f;
        for (int c = 0; c < C; ++c) dot += xi[c] * xq[c];
        dist[q] = sqp + sqn[base + q] - 2.0f * dot;
    }
    __syncthreads();

    for (int r = 0; r < KNN; ++r) {
        unsigned long long best = ~0ull;
        for (int q = tid; q < NP; q += 256) {
            float dv = dist[q];
            unsigned u = __float_as_uint(dv);
            u = (u & 0x80000000u) ? ~u : (u | 0x80000000u);  // order-preserving map
            unsigned long long key = ((unsigned long long)u << 32) | (unsigned)q;
            best = umin64(best, key);
        }
        rkey[tid] = best;
        __syncthreads();
        for (int s = 128; s > 0; s >>= 1) {
            if (tid < s) rkey[tid] = umin64(rkey[tid], rkey[tid + s]);
            __syncthreads();
        }
        if (tid == 0) {
            int q = (int)(rkey[0] & 0xffffffffu);
            idx[p * KNN + r] = q;
            dist[q] = __uint_as_float(0x7f800000u);  // +inf, remove from candidates
        }
        __syncthreads();
    }
}

// ---------------- EdgeConv: y[p,co] = max_j ( [xi, xj-xi] . W[:,co] ) + b[co] ----------------
template <int Cin, int Cout>
__global__ __launch_bounds__(Cout) void edge_conv_kernel(const float* __restrict__ x,
                                                         const int* __restrict__ idx,
                                                         const float* __restrict__ W,
                                                         const float* __restrict__ b,
                                                         float* __restrict__ y) {
    const int p = blockIdx.x;
    const int base = (p >> 10) << 10;
    const int co = threadIdx.x;  // blockDim == Cout

    __shared__ float s_xi[Cin];
    __shared__ float s_dx[KNN][Cin];
    __shared__ int s_idx[KNN];

    if (co < KNN) s_idx[co] = idx[p * KNN + co];
    for (int c = co; c < Cin; c += Cout) s_xi[c] = x[(size_t)p * Cin + c];
    __syncthreads();

    for (int t = co; t < KNN * Cin; t += Cout) {
        int j = t / Cin, c = t - j * Cin;
        int q = s_idx[j];
        s_dx[j][c] = x[(size_t)(base + q) * Cin + c] - s_xi[c];
    }
    __syncthreads();

    float acc[KNN];
#pragma unroll
    for (int j = 0; j < KNN; ++j) acc[j] = 0.f;

    for (int c = 0; c < Cin; ++c) {
        float w1 = W[c * Cout + co];
        float w2 = W[(Cin + c) * Cout + co];
        float t1 = s_xi[c] * w1;
#pragma unroll
        for (int j = 0; j < KNN; ++j) acc[j] += t1 + s_dx[j][c] * w2;
    }

    float m = acc[0];
#pragma unroll
    for (int j = 1; j < KNN; ++j) m = fmaxf(m, acc[j]);
    y[(size_t)p * Cout + co] = m + b[co];
}

// ---------------- cat(x1..x4) @ Wm + bm : [8192,512] x [512,1024] ----------------
__global__ __launch_bounds__(256) void gemm_cat_kernel(const float* __restrict__ x1,
                                                       const float* __restrict__ x2,
                                                       const float* __restrict__ x3,
                                                       const float* __restrict__ x4,
                                                       const float* __restrict__ Wm,
                                                       const float* __restrict__ bm,
                                                       float* __restrict__ out) {
    const int pb = blockIdx.x * 8;  // 8 points per block
    const int tid = threadIdx.x;
    __shared__ float s_cat[8][512];

    for (int t = tid; t < 8 * 512; t += 256) {
        int pp = t >> 9, c = t & 511;
        int p = pb + pp;
        float v;
        if (c < 64) v = x1[(size_t)p * 64 + c];
        else if (c < 128) v = x2[(size_t)p * 64 + (c - 64)];
        else if (c < 256) v = x3[(size_t)p * 128 + (c - 128)];
        else v = x4[(size_t)p * 256 + (c - 256)];
        s_cat[pp][c] = v;
    }
    __syncthreads();

    float acc[8][4];
#pragma unroll
    for (int pp = 0; pp < 8; ++pp)
#pragma unroll
        for (int k = 0; k < 4; ++k) acc[pp][k] = 0.f;

    for (int c = 0; c < 512; ++c) {
        float w0 = Wm[c * 1024 + tid];
        float w1 = Wm[c * 1024 + tid + 256];
        float w2 = Wm[c * 1024 + tid + 512];
        float w3 = Wm[c * 1024 + tid + 768];
#pragma unroll
        for (int pp = 0; pp < 8; ++pp) {
            float xc = s_cat[pp][c];
            acc[pp][0] += xc * w0;
            acc[pp][1] += xc * w1;
            acc[pp][2] += xc * w2;
            acc[pp][3] += xc * w3;
        }
    }
#pragma unroll
    for (int pp = 0; pp < 8; ++pp)
#pragma unroll
        for (int k = 0; k < 4; ++k)
            out[(size_t)(pb + pp) * 1024 + tid + k * 256] = acc[pp][k] + bm[tid + k * 256];
}

// ---------------- global max+mean pool over P ----------------
__global__ __launch_bounds__(256) void pool_kernel(const float* __restrict__ out,
                                                   float* __restrict__ gmax,
                                                   float* __restrict__ gmean) {
    int b = blockIdx.y;
    int co = blockIdx.x * 256 + threadIdx.x;  // 0..1023
    const float* pb = out + (size_t)b * NP * 1024 + co;
    float m = -__builtin_inff(), s = 0.f;
    for (int p = 0; p < NP; ++p) {
        float v = pb[(size_t)p * 1024];
        m = fmaxf(m, v);
        s += v;
    }
    gmax[b * 1024 + co] = m;
    gmean[b * 1024 + co] = s * (1.0f / 1024.0f);
}

// ---------------- head ----------------
__global__ __launch_bounds__(256) void fc_a_kernel(const float* __restrict__ gmax,
                                                   const float* __restrict__ gmean,
                                                   const float* __restrict__ Wa,
                                                   const float* __restrict__ ba,
                                                   float* __restrict__ ha) {
    int t = blockIdx.x * 256 + threadIdx.x;  // 8*512
    if (t >= 8 * 512) return;
    int b = t >> 9, co = t & 511;
    float s = ba[co];
    for (int c = 0; c < 1024; ++c) s += gmax[b * 1024 + c] * Wa[c * 512 + co];
    for (int c = 0; c < 1024; ++c) s += gmean[b * 1024 + c] * Wa[(1024 + c) * 512 + co];
    ha[t] = s;
}

__global__ __launch_bounds__(256) void bn_leaky_kernel(float* __restrict__ h,
                                                       const float* __restrict__ g,
                                                       const float* __restrict__ be,
                                                       int ncol) {
    int co = blockIdx.x * 256 + threadIdx.x;
    if (co >= ncol) return;
    float mu = 0.f;
    for (int b = 0; b < NB; ++b) mu += h[b * ncol + co];
    mu *= 0.125f;
    float var = 0.f;
    for (int b = 0; b < NB; ++b) {
        float d = h[b * ncol + co] - mu;
        var += d * d;
    }
    var *= 0.125f;
    float inv = 1.0f / sqrtf(var + 1e-5f);
    for (int b = 0; b < NB; ++b) {
        float v = (h[b * ncol + co] - mu) * inv * g[co] + be[co];
        h[b * ncol + co] = v >= 0.f ? v : 0.2f * v;
    }
}

__global__ __launch_bounds__(256) void fc_b_kernel(const float* __restrict__ ha,
                                                   const float* __restrict__ Wb,
                                                   const float* __restrict__ bb,
                                                   float* __restrict__ hb) {
    int t = blockIdx.x * 256 + threadIdx.x;  // 8*256
    if (t >= 8 * 256) return;
    int b = t >> 8, co = t & 255;
    float s = bb[co];
    for (int c = 0; c < 512; ++c) s += ha[b * 512 + c] * Wb[c * 256 + co];
    hb[t] = s;
}

__global__ __launch_bounds__(256) void fc_c_kernel(const float* __restrict__ hb,
                                                   const float* __restrict__ Wc,
                                                   const float* __restrict__ bc,
                                                   float* __restrict__ outp) {
    int t = blockIdx.x * 256 + threadIdx.x;  // 8*40
    if (t >= 8 * 40) return;
    int b = t / 40, o = t - b * 40;
    float s = bc[o];
    for (int c = 0; c < 256; ++c) s += hb[b * 256 + c] * Wc[c * 40 + o];
    outp[t] = s;
}

extern "C" void kernel_launch(void* const* d_in, const int* in_sizes, int n_in,
                              void* d_out, int out_size, void* d_ws, size_t ws_size,
                              hipStream_t stream) {
    const float* pos = (const float*)d_in[0];
    // d_in[1] = batch (contiguous, unused)
    const float* W1 = (const float*)d_in[2];
    const float* b1 = (const float*)d_in[3];
    const float* W2 = (const float*)d_in[4];
    const float* b2 = (const float*)d_in[5];
    const float* W3 = (const float*)d_in[6];
    const float* b3 = (const float*)d_in[7];
    const float* W4 = (const float*)d_in[8];
    const float* b4 = (const float*)d_in[9];
    const float* Wm = (const float*)d_in[10];
    const float* bm = (const float*)d_in[11];
    const float* Wa = (const float*)d_in[12];
    const float* ba = (const float*)d_in[13];
    const float* ga = (const float*)d_in[14];
    const float* bea = (const float*)d_in[15];
    const float* Wb = (const float*)d_in[16];
    const float* bb = (const float*)d_in[17];
    const float* gb = (const float*)d_in[18];
    const float* beb = (const float*)d_in[19];
    const float* Wc = (const float*)d_in[20];
    const float* bc = (const float*)d_in[21];
    float* out = (float*)d_out;

    // workspace layout
    char* ws = (char*)d_ws;
    size_t off = 0;
    auto alloc = [&](size_t bytes) {
        void* p = ws + off;
        off += (bytes + 255) & ~(size_t)255;
        return p;
    };
    float* sqn = (float*)alloc(NPTS * 4);
    int* idx = (int*)alloc((size_t)NPTS * KNN * 4);
    float* x1 = (float*)alloc((size_t)NPTS * 64 * 4);
    float* x2 = (float*)alloc((size_t)NPTS * 64 * 4);
    float* x3 = (float*)alloc((size_t)NPTS * 128 * 4);
    float* x4 = (float*)alloc((size_t)NPTS * 256 * 4);
    float* outm = (float*)alloc((size_t)NPTS * 1024 * 4);
    float* gmax = (float*)alloc(NB * 1024 * 4);
    float* gmean = (float*)alloc(NB * 1024 * 4);
    float* ha = (float*)alloc(NB * 512 * 4);
    float* hb = (float*)alloc(NB * 256 * 4);
    (void)ws_size;

    // layer 1 (C=3 -> 64)
    sqnorm_kernel<3><<<NPTS / 256, 256, 0, stream>>>(pos, sqn);
    knn_kernel<3><<<NPTS, 256, 0, stream>>>(pos, sqn, idx);
    edge_conv_kernel<3, 64><<<NPTS, 64, 0, stream>>>(pos, idx, W1, b1, x1);

    // layer 2 (64 -> 64)
    sqnorm_kernel<64><<<NPTS / 256, 256, 0, stream>>>(x1, sqn);
    knn_kernel<64><<<NPTS, 256, 0, stream>>>(x1, sqn, idx);
    edge_conv_kernel<64, 64><<<NPTS, 64, 0, stream>>>(x1, idx, W2, b2, x2);

    // layer 3 (64 -> 128)
    sqnorm_kernel<64><<<NPTS / 256, 256, 0, stream>>>(x2, sqn);
    knn_kernel<64><<<NPTS, 256, 0, stream>>>(x2, sqn, idx);
    edge_conv_kernel<64, 128><<<NPTS, 128, 0, stream>>>(x2, idx, W3, b3, x3);

    // layer 4 (128 -> 256)
    sqnorm_kernel<128><<<NPTS / 256, 256, 0, stream>>>(x3, sqn);
    knn_kernel<128><<<NPTS, 256, 0, stream>>>(x3, sqn, idx);
    edge_conv_kernel<128, 256><<<NPTS, 256, 0, stream>>>(x3, idx, W4, b4, x4);

    // cat @ Wm + bm
    gemm_cat_kernel<<<NPTS / 8, 256, 0, stream>>>(x1, x2, x3, x4, Wm, bm, outm);

    // pooling
    pool_kernel<<<dim3(4, NB), 256, 0, stream>>>(outm, gmax, gmean);

    // head
    fc_a_kernel<<<16, 256, 0, stream>>>(gmax, gmean, Wa, ba, ha);
    bn_leaky_kernel<<<2, 256, 0, stream>>>(ha, ga, bea, 512);
    fc_b_kernel<<<8, 256, 0, stream>>>(ha, Wb, bb, hb);
    bn_leaky_kernel<<<1, 256, 0, stream>>>(hb, gb, beb, 256);
    fc_c_kernel<<<2, 256, 0, stream>>>(hb, Wc, bc, out);
}

// Round 2
// 1079.808 us; speedup vs baseline: 2.1167x; 2.1167x over previous
//
#include <hip/hip_runtime.h>
#include <hip/hip_bf16.h>

#define NB 8
#define NP 1024
#define NPTS (NB * NP)
#define KNN 20

static __device__ __forceinline__ unsigned long long umin64(unsigned long long a,
                                                            unsigned long long b) {
    return a < b ? a : b;
}

// ---------------- squared norms ----------------
template <int C>
__global__ __launch_bounds__(256) void sqnorm_kernel(const float* __restrict__ x,
                                                     float* __restrict__ sqn) {
    int p = blockIdx.x * 256 + threadIdx.x;
    if (p < NPTS) {
        const float* xp = x + (size_t)p * C;
        float s = 0.f;
        for (int c = 0; c < C; ++c) s += xp[c] * xp[c];
        sqn[p] = s;
    }
}

// ---------------- distance matrix: D[b][p][q] = sq[p]+sq[q]-2*dot(x_p,x_q) ----------------
// grid (16,16,8), block 256 (16x16 logical), 64x64 tile per block, 4x4 per thread.
template <int C>
__global__ __launch_bounds__(256) void dist_kernel(const float* __restrict__ x,
                                                   const float* __restrict__ sqn,
                                                   float* __restrict__ Dm) {
    constexpr int BK = (C < 32) ? C : 32;
    const int b = blockIdx.z;
    const int p0 = blockIdx.y * 64;
    const int q0 = blockIdx.x * 64;
    const int tid = threadIdx.x;
    const int tx = tid & 15, ty = tid >> 4;
    const float* xb = x + (size_t)b * NP * C;
    const float* sb = sqn + b * NP;

    __shared__ float sA[64][BK + 1];
    __shared__ float sB[64][BK + 1];

    float acc[4][4];
#pragma unroll
    for (int i = 0; i < 4; ++i)
#pragma unroll
        for (int j = 0; j < 4; ++j) acc[i][j] = 0.f;

    for (int k0 = 0; k0 < C; k0 += BK) {
        for (int t = tid; t < 64 * BK; t += 256) {
            int row = t / BK, col = t - row * BK;
            sA[row][col] = xb[(size_t)(p0 + row) * C + k0 + col];
            sB[row][col] = xb[(size_t)(q0 + row) * C + k0 + col];
        }
        __syncthreads();
#pragma unroll 4
        for (int c = 0; c < BK; ++c) {
            float a4[4], b4[4];
#pragma unroll
            for (int i = 0; i < 4; ++i) a4[i] = sA[ty * 4 + i][c];
#pragma unroll
            for (int j = 0; j < 4; ++j) b4[j] = sB[tx * 4 + j][c];
#pragma unroll
            for (int i = 0; i < 4; ++i)
#pragma unroll
                for (int j = 0; j < 4; ++j) acc[i][j] += a4[i] * b4[j];
        }
        __syncthreads();
    }

#pragma unroll
    for (int i = 0; i < 4; ++i) {
        int p = p0 + ty * 4 + i;
        float sqp = sb[p];
        float* drow = Dm + ((size_t)b * NP + p) * NP + q0;
#pragma unroll
        for (int j = 0; j < 4; ++j) {
            int q = tx * 4 + j;
            drow[q] = sqp + sb[q0 + q] - 2.0f * acc[i][j];
        }
    }
}

// ---------------- top-20 per row, wave-local (no barriers, no LDS) ----------------
__global__ __launch_bounds__(256) void topk_kernel(const float* __restrict__ Dm,
                                                   int* __restrict__ idx) {
    const int w = threadIdx.x >> 6, lane = threadIdx.x & 63;
    const int p = blockIdx.x * 4 + w;
    const int b = p >> 10, pr = p & 1023;
    const float* row = Dm + ((size_t)b * NP + pr) * NP;

    unsigned long long k[16];
#pragma unroll
    for (int j = 0; j < 16; ++j) {
        int q = j * 64 + lane;
        float dv = row[q];
        unsigned u = __float_as_uint(dv);
        u = (u & 0x80000000u) ? ~u : (u | 0x80000000u);  // order-preserving map
        k[j] = ((unsigned long long)u << 32) | (unsigned)q;
    }

    for (int r = 0; r < KNN; ++r) {
        unsigned long long m = k[0];
#pragma unroll
        for (int j = 1; j < 16; ++j) m = umin64(m, k[j]);
#pragma unroll
        for (int s = 1; s < 64; s <<= 1) {
            unsigned long long o = __shfl_xor(m, s, 64);
            m = umin64(m, o);
        }
        if (lane == 0) idx[p * KNN + r] = (int)(m & 0xffffffffu);
#pragma unroll
        for (int j = 0; j < 16; ++j)
            if (k[j] == m) k[j] = ~0ull;
    }
}

// ---------------- EdgeConv: y[p,co] = max_j ( [xi, xj-xi] . W[:,co] ) + b[co] ----------------
template <int Cin, int Cout>
__global__ __launch_bounds__(Cout) void edge_conv_kernel(const float* __restrict__ x,
                                                         const int* __restrict__ idx,
                                                         const float* __restrict__ W,
                                                         const float* __restrict__ b,
                                                         float* __restrict__ y) {
    const int p = blockIdx.x;
    const int base = (p >> 10) << 10;
    const int co = threadIdx.x;  // blockDim == Cout

    __shared__ float s_xi[Cin];
    __shared__ float s_dx[KNN][Cin];
    __shared__ int s_idx[KNN];

    if (co < KNN) s_idx[co] = idx[p * KNN + co];
    for (int c = co; c < Cin; c += Cout) s_xi[c] = x[(size_t)p * Cin + c];
    __syncthreads();

    for (int t = co; t < KNN * Cin; t += Cout) {
        int j = t / Cin, c = t - j * Cin;
        int q = s_idx[j];
        s_dx[j][c] = x[(size_t)(base + q) * Cin + c] - s_xi[c];
    }
    __syncthreads();

    float acc[KNN];
#pragma unroll
    for (int j = 0; j < KNN; ++j) acc[j] = 0.f;

    for (int c = 0; c < Cin; ++c) {
        float w1 = W[c * Cout + co];
        float w2 = W[(Cin + c) * Cout + co];
        float t1 = s_xi[c] * w1;
#pragma unroll
        for (int j = 0; j < KNN; ++j) acc[j] += t1 + s_dx[j][c] * w2;
    }

    float m = acc[0];
#pragma unroll
    for (int j = 1; j < KNN; ++j) m = fmaxf(m, acc[j]);
    y[(size_t)p * Cout + co] = m + b[co];
}

// ---------------- cat(x1..x4) @ Wm + bm : [8192,512] x [512,1024] ----------------
__global__ __launch_bounds__(256) void gemm_cat_kernel(const float* __restrict__ x1,
                                                       const float* __restrict__ x2,
                                                       const float* __restrict__ x3,
                                                       const float* __restrict__ x4,
                                                       const float* __restrict__ Wm,
                                                       const float* __restrict__ bm,
                                                       float* __restrict__ out) {
    const int pb = blockIdx.x * 8;  // 8 points per block
    const int tid = threadIdx.x;
    __shared__ float s_cat[8][512];

    for (int t = tid; t < 8 * 512; t += 256) {
        int pp = t >> 9, c = t & 511;
        int p = pb + pp;
        float v;
        if (c < 64) v = x1[(size_t)p * 64 + c];
        else if (c < 128) v = x2[(size_t)p * 64 + (c - 64)];
        else if (c < 256) v = x3[(size_t)p * 128 + (c - 128)];
        else v = x4[(size_t)p * 256 + (c - 256)];
        s_cat[pp][c] = v;
    }
    __syncthreads();

    float acc[8][4];
#pragma unroll
    for (int pp = 0; pp < 8; ++pp)
#pragma unroll
        for (int k = 0; k < 4; ++k) acc[pp][k] = 0.f;

    for (int c = 0; c < 512; ++c) {
        float w0 = Wm[c * 1024 + tid];
        float w1 = Wm[c * 1024 + tid + 256];
        float w2 = Wm[c * 1024 + tid + 512];
        float w3 = Wm[c * 1024 + tid + 768];
#pragma unroll
        for (int pp = 0; pp < 8; ++pp) {
            float xc = s_cat[pp][c];
            acc[pp][0] += xc * w0;
            acc[pp][1] += xc * w1;
            acc[pp][2] += xc * w2;
            acc[pp][3] += xc * w3;
        }
    }
#pragma unroll
    for (int pp = 0; pp < 8; ++pp)
#pragma unroll
        for (int k = 0; k < 4; ++k)
            out[(size_t)(pb + pp) * 1024 + tid + k * 256] = acc[pp][k] + bm[tid + k * 256];
}

// ---------------- global max+mean pool over P ----------------
__global__ __launch_bounds__(256) void pool_kernel(const float* __restrict__ out,
                                                   float* __restrict__ gmax,
                                                   float* __restrict__ gmean) {
    int b = blockIdx.y;
    int co = blockIdx.x * 256 + threadIdx.x;  // 0..1023
    const float* pb = out + (size_t)b * NP * 1024 + co;
    float m = -__builtin_inff(), s = 0.f;
    for (int p = 0; p < NP; ++p) {
        float v = pb[(size_t)p * 1024];
        m = fmaxf(m, v);
        s += v;
    }
    gmax[b * 1024 + co] = m;
    gmean[b * 1024 + co] = s * (1.0f / 1024.0f);
}

// ---------------- head ----------------
__global__ __launch_bounds__(256) void fc_a_kernel(const float* __restrict__ gmax,
                                                   const float* __restrict__ gmean,
                                                   const float* __restrict__ Wa,
                                                   const float* __restrict__ ba,
                                                   float* __restrict__ ha) {
    int t = blockIdx.x * 256 + threadIdx.x;  // 8*512
    if (t >= 8 * 512) return;
    int b = t >> 9, co = t & 511;
    float s = ba[co];
    for (int c = 0; c < 1024; ++c) s += gmax[b * 1024 + c] * Wa[c * 512 + co];
    for (int c = 0; c < 1024; ++c) s += gmean[b * 1024 + c] * Wa[(1024 + c) * 512 + co];
    ha[t] = s;
}

__global__ __launch_bounds__(256) void bn_leaky_kernel(float* __restrict__ h,
                                                       const float* __restrict__ g,
                                                       const float* __restrict__ be,
                                                       int ncol) {
    int co = blockIdx.x * 256 + threadIdx.x;
    if (co >= ncol) return;
    float mu = 0.f;
    for (int b = 0; b < NB; ++b) mu += h[b * ncol + co];
    mu *= 0.125f;
    float var = 0.f;
    for (int b = 0; b < NB; ++b) {
        float d = h[b * ncol + co] - mu;
        var += d * d;
    }
    var *= 0.125f;
    float inv = 1.0f / sqrtf(var + 1e-5f);
    for (int b = 0; b < NB; ++b) {
        float v = (h[b * ncol + co] - mu) * inv * g[co] + be[co];
        h[b * ncol + co] = v >= 0.f ? v : 0.2f * v;
    }
}

__global__ __launch_bounds__(256) void fc_b_kernel(const float* __restrict__ ha,
                                                   const float* __restrict__ Wb,
                                                   const float* __restrict__ bb,
                                                   float* __restrict__ hb) {
    int t = blockIdx.x * 256 + threadIdx.x;  // 8*256
    if (t >= 8 * 256) return;
    int b = t >> 8, co = t & 255;
    float s = bb[co];
    for (int c = 0; c < 512; ++c) s += ha[b * 512 + c] * Wb[c * 256 + co];
    hb[t] = s;
}

__global__ __launch_bounds__(256) void fc_c_kernel(const float* __restrict__ hb,
                                                   const float* __restrict__ Wc,
                                                   const float* __restrict__ bc,
                                                   float* __restrict__ outp) {
    int t = blockIdx.x * 256 + threadIdx.x;  // 8*40
    if (t >= 8 * 40) return;
    int b = t / 40, o = t - b * 40;
    float s = bc[o];
    for (int c = 0; c < 256; ++c) s += hb[b * 256 + c] * Wc[c * 40 + o];
    outp[t] = s;
}

extern "C" void kernel_launch(void* const* d_in, const int* in_sizes, int n_in,
                              void* d_out, int out_size, void* d_ws, size_t ws_size,
                              hipStream_t stream) {
    const float* pos = (const float*)d_in[0];
    const float* W1 = (const float*)d_in[2];
    const float* b1 = (const float*)d_in[3];
    const float* W2 = (const float*)d_in[4];
    const float* b2 = (const float*)d_in[5];
    const float* W3 = (const float*)d_in[6];
    const float* b3 = (const float*)d_in[7];
    const float* W4 = (const float*)d_in[8];
    const float* b4 = (const float*)d_in[9];
    const float* Wm = (const float*)d_in[10];
    const float* bm = (const float*)d_in[11];
    const float* Wa = (const float*)d_in[12];
    const float* ba = (const float*)d_in[13];
    const float* ga = (const float*)d_in[14];
    const float* bea = (const float*)d_in[15];
    const float* Wb = (const float*)d_in[16];
    const float* bb = (const float*)d_in[17];
    const float* gb = (const float*)d_in[18];
    const float* beb = (const float*)d_in[19];
    const float* Wc = (const float*)d_in[20];
    const float* bc = (const float*)d_in[21];
    float* out = (float*)d_out;

    char* ws = (char*)d_ws;
    size_t off = 0;
    auto alloc = [&](size_t bytes) {
        void* p = ws + off;
        off += (bytes + 255) & ~(size_t)255;
        return p;
    };
    float* sqn = (float*)alloc(NPTS * 4);
    int* idx = (int*)alloc((size_t)NPTS * KNN * 4);
    float* x1 = (float*)alloc((size_t)NPTS * 64 * 4);
    float* x2 = (float*)alloc((size_t)NPTS * 64 * 4);
    float* x3 = (float*)alloc((size_t)NPTS * 128 * 4);
    float* x4 = (float*)alloc((size_t)NPTS * 256 * 4);
    float* outm = (float*)alloc((size_t)NPTS * 1024 * 4);
    float* gmax = (float*)alloc(NB * 1024 * 4);
    float* gmean = (float*)alloc(NB * 1024 * 4);
    float* ha = (float*)alloc(NB * 512 * 4);
    float* hb = (float*)alloc(NB * 256 * 4);
    (void)ws_size;

    // Dm aliases outm: Dm is only live before gemm_cat writes outm.
    float* Dm = outm;

    dim3 dgrid(16, 16, 8);

    // layer 1 (C=3 -> 64)
    sqnorm_kernel<3><<<NPTS / 256, 256, 0, stream>>>(pos, sqn);
    dist_kernel<3><<<dgrid, 256, 0, stream>>>(pos, sqn, Dm);
    topk_kernel<<<NPTS / 4, 256, 0, stream>>>(Dm, idx);
    edge_conv_kernel<3, 64><<<NPTS, 64, 0, stream>>>(pos, idx, W1, b1, x1);

    // layer 2 (64 -> 64)
    sqnorm_kernel<64><<<NPTS / 256, 256, 0, stream>>>(x1, sqn);
    dist_kernel<64><<<dgrid, 256, 0, stream>>>(x1, sqn, Dm);
    topk_kernel<<<NPTS / 4, 256, 0, stream>>>(Dm, idx);
    edge_conv_kernel<64, 64><<<NPTS, 64, 0, stream>>>(x1, idx, W2, b2, x2);

    // layer 3 (64 -> 128)
    sqnorm_kernel<64><<<NPTS / 256, 256, 0, stream>>>(x2, sqn);
    dist_kernel<64><<<dgrid, 256, 0, stream>>>(x2, sqn, Dm);
    topk_kernel<<<NPTS / 4, 256, 0, stream>>>(Dm, idx);
    edge_conv_kernel<64, 128><<<NPTS, 128, 0, stream>>>(x2, idx, W3, b3, x3);

    // layer 4 (128 -> 256)
    sqnorm_kernel<128><<<NPTS / 256, 256, 0, stream>>>(x3, sqn);
    dist_kernel<128><<<dgrid, 256, 0, stream>>>(x3, sqn, Dm);
    topk_kernel<<<NPTS / 4, 256, 0, stream>>>(Dm, idx);
    edge_conv_kernel<128, 256><<<NPTS, 256, 0, stream>>>(x3, idx, W4, b4, x4);

    // cat @ Wm + bm   (overwrites Dm/outm — safe, Dm no longer needed)
    gemm_cat_kernel<<<NPTS / 8, 256, 0, stream>>>(x1, x2, x3, x4, Wm, bm, outm);

    // pooling
    pool_kernel<<<dim3(4, NB), 256, 0, stream>>>(outm, gmax, gmean);

    // head
    fc_a_kernel<<<16, 256, 0, stream>>>(gmax, gmean, Wa, ba, ha);
    bn_leaky_kernel<<<2, 256, 0, stream>>>(ha, ga, bea, 512);
    fc_b_kernel<<<8, 256, 0, stream>>>(ha, Wb, bb, hb);
    bn_leaky_kernel<<<1, 256, 0, stream>>>(hb, gb, beb, 256);
    fc_c_kernel<<<2, 256, 0, stream>>>(hb, Wc, bc, out);
}

// Round 3
// 701.460 us; speedup vs baseline: 3.2583x; 1.5394x over previous
//
#include <hip/hip_runtime.h>
#include <hip/hip_bf16.h>

#define NB 8
#define NP 1024
#define NPTS (NB * NP)
#define KNN 20

static __device__ __forceinline__ unsigned long long umin64(unsigned long long a,
                                                            unsigned long long b) {
    return a < b ? a : b;
}

// ---------------- squared norms ----------------
template <int C>
__global__ __launch_bounds__(256) void sqnorm_kernel(const float* __restrict__ x,
                                                     float* __restrict__ sqn) {
    int p = blockIdx.x * 256 + threadIdx.x;
    if (p < NPTS) {
        const float* xp = x + (size_t)p * C;
        float s = 0.f;
        for (int c = 0; c < C; ++c) s += xp[c] * xp[c];
        sqn[p] = s;
    }
}

// ---------------- distance matrix: D[b][p][q] = sq[p]+sq[q]-2*dot(x_p,x_q) ----------------
template <int C>
__global__ __launch_bounds__(256) void dist_kernel(const float* __restrict__ x,
                                                   const float* __restrict__ sqn,
                                                   float* __restrict__ Dm) {
    constexpr int BK = (C < 32) ? C : 32;
    const int b = blockIdx.z;
    const int p0 = blockIdx.y * 64;
    const int q0 = blockIdx.x * 64;
    const int tid = threadIdx.x;
    const int tx = tid & 15, ty = tid >> 4;
    const float* xb = x + (size_t)b * NP * C;
    const float* sb = sqn + b * NP;

    __shared__ float sA[64][BK + 1];
    __shared__ float sB[64][BK + 1];

    float acc[4][4];
#pragma unroll
    for (int i = 0; i < 4; ++i)
#pragma unroll
        for (int j = 0; j < 4; ++j) acc[i][j] = 0.f;

    for (int k0 = 0; k0 < C; k0 += BK) {
        for (int t = tid; t < 64 * BK; t += 256) {
            int row = t / BK, col = t - row * BK;
            sA[row][col] = xb[(size_t)(p0 + row) * C + k0 + col];
            sB[row][col] = xb[(size_t)(q0 + row) * C + k0 + col];
        }
        __syncthreads();
#pragma unroll 4
        for (int c = 0; c < BK; ++c) {
            float a4[4], b4[4];
#pragma unroll
            for (int i = 0; i < 4; ++i) a4[i] = sA[ty * 4 + i][c];
#pragma unroll
            for (int j = 0; j < 4; ++j) b4[j] = sB[tx * 4 + j][c];
#pragma unroll
            for (int i = 0; i < 4; ++i)
#pragma unroll
                for (int j = 0; j < 4; ++j) acc[i][j] += a4[i] * b4[j];
        }
        __syncthreads();
    }

#pragma unroll
    for (int i = 0; i < 4; ++i) {
        int p = p0 + ty * 4 + i;
        float sqp = sb[p];
        float* drow = Dm + ((size_t)b * NP + p) * NP + q0;
#pragma unroll
        for (int j = 0; j < 4; ++j) {
            int q = tx * 4 + j;
            drow[q] = sqp + sb[q0 + q] - 2.0f * acc[i][j];
        }
    }
}

// ---------------- top-20 per row, wave-local (no barriers, no LDS) ----------------
__global__ __launch_bounds__(256) void topk_kernel(const float* __restrict__ Dm,
                                                   int* __restrict__ idx) {
    const int w = threadIdx.x >> 6, lane = threadIdx.x & 63;
    const int p = blockIdx.x * 4 + w;
    const int b = p >> 10, pr = p & 1023;
    const float* row = Dm + ((size_t)b * NP + pr) * NP;

    unsigned long long k[16];
#pragma unroll
    for (int j = 0; j < 16; ++j) {
        int q = j * 64 + lane;
        float dv = row[q];
        unsigned u = __float_as_uint(dv);
        u = (u & 0x80000000u) ? ~u : (u | 0x80000000u);  // order-preserving map
        k[j] = ((unsigned long long)u << 32) | (unsigned)q;
    }

    for (int r = 0; r < KNN; ++r) {
        unsigned long long m = k[0];
#pragma unroll
        for (int j = 1; j < 16; ++j) m = umin64(m, k[j]);
#pragma unroll
        for (int s = 1; s < 64; s <<= 1) {
            unsigned long long o = __shfl_xor(m, s, 64);
            m = umin64(m, o);
        }
        if (lane == 0) idx[p * KNN + r] = (int)(m & 0xffffffffu);
#pragma unroll
        for (int j = 0; j < 16; ++j)
            if (k[j] == m) k[j] = ~0ull;
    }
}

// ---------------- EdgeConv as GEMM: AB[p, 0:Cout] = x_p.(W1-W2) + b ; AB[p, Cout:2Cout] = x_p.W2
template <int Cin, int Cout>
__global__ __launch_bounds__(256) void edge_gemm_kernel(const float* __restrict__ x,
                                                        const float* __restrict__ W,
                                                        const float* __restrict__ bias,
                                                        float* __restrict__ AB) {
    constexpr int N2 = 2 * Cout;
    constexpr int BK = (Cin < 32) ? Cin : 32;
    const int n0 = blockIdx.x * 64;
    const int p0 = blockIdx.y * 64;
    const bool aHalf = (n0 < Cout);  // uniform per block (Cout % 64 == 0)
    const int tid = threadIdx.x;
    const int tx = tid & 15, ty = tid >> 4;

    __shared__ float sX[64][BK + 1];
    __shared__ float sW[BK][65];

    float acc[4][4];
#pragma unroll
    for (int i = 0; i < 4; ++i)
#pragma unroll
        for (int j = 0; j < 4; ++j) acc[i][j] = 0.f;

    for (int k0 = 0; k0 < Cin; k0 += BK) {
        for (int t = tid; t < 64 * BK; t += 256) {
            int r = t / BK, c = t - r * BK;
            sX[r][c] = x[(size_t)(p0 + r) * Cin + k0 + c];
        }
        for (int t = tid; t < BK * 64; t += 256) {
            int c = t >> 6, n = t & 63;
            int nn = n0 + n;
            float w;
            if (aHalf)
                w = W[(size_t)(k0 + c) * Cout + nn] - W[(size_t)(Cin + k0 + c) * Cout + nn];
            else
                w = W[(size_t)(Cin + k0 + c) * Cout + (nn - Cout)];
            sW[c][n] = w;
        }
        __syncthreads();
#pragma unroll 4
        for (int c = 0; c < BK; ++c) {
            float a4[4], b4[4];
#pragma unroll
            for (int i = 0; i < 4; ++i) a4[i] = sX[ty * 4 + i][c];
#pragma unroll
            for (int j = 0; j < 4; ++j) b4[j] = sW[c][tx * 4 + j];
#pragma unroll
            for (int i = 0; i < 4; ++i)
#pragma unroll
                for (int j = 0; j < 4; ++j) acc[i][j] += a4[i] * b4[j];
        }
        __syncthreads();
    }

#pragma unroll
    for (int i = 0; i < 4; ++i) {
        float* orow = AB + (size_t)(p0 + ty * 4 + i) * N2 + n0 + tx * 4;
#pragma unroll
        for (int j = 0; j < 4; ++j) {
            float v = acc[i][j];
            if (aHalf) v += bias[n0 + tx * 4 + j];
            orow[j] = v;
        }
    }
}

// ---------------- y[p,co] = A[p,co] + max_j Bv[base+idx[p,j], co] ----------------
template <int Cout>
__global__ __launch_bounds__(256) void gather_max_kernel(const float* __restrict__ AB,
                                                         const int* __restrict__ idx,
                                                         float* __restrict__ y) {
    constexpr int N2 = 2 * Cout;
    constexpr int TPP = Cout / 4;   // threads per point
    constexpr int PPB = 256 / TPP;  // points per block
    constexpr int RS = N2 / 4;      // AB row stride in float4
    const int pp = threadIdx.x / TPP;
    const int t = threadIdx.x % TPP;
    const int p = blockIdx.x * PPB + pp;
    const int base = p & ~(NP - 1);

    __shared__ int s_idx[PPB][KNN];
    for (int tt = threadIdx.x; tt < PPB * KNN; tt += 256) {
        int a = tt / KNN, r = tt - a * KNN;
        s_idx[a][r] = idx[(size_t)(blockIdx.x * PPB + a) * KNN + r];
    }
    __syncthreads();

    const float4* Brow = (const float4*)(AB + (size_t)base * N2 + Cout);

    int q0 = s_idx[pp][0];
    float4 m = Brow[(size_t)q0 * RS + t];
#pragma unroll
    for (int j = 1; j < KNN; ++j) {
        int q = s_idx[pp][j];
        float4 v = Brow[(size_t)q * RS + t];
        m.x = fmaxf(m.x, v.x);
        m.y = fmaxf(m.y, v.y);
        m.z = fmaxf(m.z, v.z);
        m.w = fmaxf(m.w, v.w);
    }
    float4 a = *(const float4*)(AB + (size_t)p * N2 + 4 * t);
    float4 o;
    o.x = a.x + m.x;
    o.y = a.y + m.y;
    o.z = a.z + m.z;
    o.w = a.w + m.w;
    *(float4*)(y + (size_t)p * Cout + 4 * t) = o;
}

// ---------------- cat(x1..x4) @ Wm + bm : [8192,512] x [512,1024] ----------------
__global__ __launch_bounds__(256) void gemm_cat_kernel(const float* __restrict__ x1,
                                                       const float* __restrict__ x2,
                                                       const float* __restrict__ x3,
                                                       const float* __restrict__ x4,
                                                       const float* __restrict__ Wm,
                                                       const float* __restrict__ bm,
                                                       float* __restrict__ out) {
    const int pb = blockIdx.x * 8;  // 8 points per block
    const int tid = threadIdx.x;
    __shared__ float s_cat[8][512];

    for (int t = tid; t < 8 * 512; t += 256) {
        int pp = t >> 9, c = t & 511;
        int p = pb + pp;
        float v;
        if (c < 64) v = x1[(size_t)p * 64 + c];
        else if (c < 128) v = x2[(size_t)p * 64 + (c - 64)];
        else if (c < 256) v = x3[(size_t)p * 128 + (c - 128)];
        else v = x4[(size_t)p * 256 + (c - 256)];
        s_cat[pp][c] = v;
    }
    __syncthreads();

    float acc[8][4];
#pragma unroll
    for (int pp = 0; pp < 8; ++pp)
#pragma unroll
        for (int k = 0; k < 4; ++k) acc[pp][k] = 0.f;

    for (int c = 0; c < 512; ++c) {
        float w0 = Wm[c * 1024 + tid];
        float w1 = Wm[c * 1024 + tid + 256];
        float w2 = Wm[c * 1024 + tid + 512];
        float w3 = Wm[c * 1024 + tid + 768];
#pragma unroll
        for (int pp = 0; pp < 8; ++pp) {
            float xc = s_cat[pp][c];
            acc[pp][0] += xc * w0;
            acc[pp][1] += xc * w1;
            acc[pp][2] += xc * w2;
            acc[pp][3] += xc * w3;
        }
    }
#pragma unroll
    for (int pp = 0; pp < 8; ++pp)
#pragma unroll
        for (int k = 0; k < 4; ++k)
            out[(size_t)(pb + pp) * 1024 + tid + k * 256] = acc[pp][k] + bm[tid + k * 256];
}

// ---------------- global max+mean pool over P ----------------
__global__ __launch_bounds__(256) void pool_kernel(const float* __restrict__ out,
                                                   float* __restrict__ gmax,
                                                   float* __restrict__ gmean) {
    int b = blockIdx.y;
    int co = blockIdx.x * 256 + threadIdx.x;  // 0..1023
    const float* pb = out + (size_t)b * NP * 1024 + co;
    float m = -__builtin_inff(), s = 0.f;
    for (int p = 0; p < NP; ++p) {
        float v = pb[(size_t)p * 1024];
        m = fmaxf(m, v);
        s += v;
    }
    gmax[b * 1024 + co] = m;
    gmean[b * 1024 + co] = s * (1.0f / 1024.0f);
}

// ---------------- head ----------------
__global__ __launch_bounds__(256) void fc_a_kernel(const float* __restrict__ gmax,
                                                   const float* __restrict__ gmean,
                                                   const float* __restrict__ Wa,
                                                   const float* __restrict__ ba,
                                                   float* __restrict__ ha) {
    int t = blockIdx.x * 256 + threadIdx.x;  // 8*512
    if (t >= 8 * 512) return;
    int b = t >> 9, co = t & 511;
    float s = ba[co];
    for (int c = 0; c < 1024; ++c) s += gmax[b * 1024 + c] * Wa[c * 512 + co];
    for (int c = 0; c < 1024; ++c) s += gmean[b * 1024 + c] * Wa[(1024 + c) * 512 + co];
    ha[t] = s;
}

__global__ __launch_bounds__(256) void bn_leaky_kernel(float* __restrict__ h,
                                                       const float* __restrict__ g,
                                                       const float* __restrict__ be,
                                                       int ncol) {
    int co = blockIdx.x * 256 + threadIdx.x;
    if (co >= ncol) return;
    float mu = 0.f;
    for (int b = 0; b < NB; ++b) mu += h[b * ncol + co];
    mu *= 0.125f;
    float var = 0.f;
    for (int b = 0; b < NB; ++b) {
        float d = h[b * ncol + co] - mu;
        var += d * d;
    }
    var *= 0.125f;
    float inv = 1.0f / sqrtf(var + 1e-5f);
    for (int b = 0; b < NB; ++b) {
        float v = (h[b * ncol + co] - mu) * inv * g[co] + be[co];
        h[b * ncol + co] = v >= 0.f ? v : 0.2f * v;
    }
}

__global__ __launch_bounds__(256) void fc_b_kernel(const float* __restrict__ ha,
                                                   const float* __restrict__ Wb,
                                                   const float* __restrict__ bb,
                                                   float* __restrict__ hb) {
    int t = blockIdx.x * 256 + threadIdx.x;  // 8*256
    if (t >= 8 * 256) return;
    int b = t >> 8, co = t & 255;
    float s = bb[co];
    for (int c = 0; c < 512; ++c) s += ha[b * 512 + c] * Wb[c * 256 + co];
    hb[t] = s;
}

__global__ __launch_bounds__(256) void fc_c_kernel(const float* __restrict__ hb,
                                                   const float* __restrict__ Wc,
                                                   const float* __restrict__ bc,
                                                   float* __restrict__ outp) {
    int t = blockIdx.x * 256 + threadIdx.x;  // 8*40
    if (t >= 8 * 40) return;
    int b = t / 40, o = t - b * 40;
    float s = bc[o];
    for (int c = 0; c < 256; ++c) s += hb[b * 256 + c] * Wc[c * 40 + o];
    outp[t] = s;
}

extern "C" void kernel_launch(void* const* d_in, const int* in_sizes, int n_in,
                              void* d_out, int out_size, void* d_ws, size_t ws_size,
                              hipStream_t stream) {
    const float* pos = (const float*)d_in[0];
    const float* W1 = (const float*)d_in[2];
    const float* b1 = (const float*)d_in[3];
    const float* W2 = (const float*)d_in[4];
    const float* b2 = (const float*)d_in[5];
    const float* W3 = (const float*)d_in[6];
    const float* b3 = (const float*)d_in[7];
    const float* W4 = (const float*)d_in[8];
    const float* b4 = (const float*)d_in[9];
    const float* Wm = (const float*)d_in[10];
    const float* bm = (const float*)d_in[11];
    const float* Wa = (const float*)d_in[12];
    const float* ba = (const float*)d_in[13];
    const float* ga = (const float*)d_in[14];
    const float* bea = (const float*)d_in[15];
    const float* Wb = (const float*)d_in[16];
    const float* bb = (const float*)d_in[17];
    const float* gb = (const float*)d_in[18];
    const float* beb = (const float*)d_in[19];
    const float* Wc = (const float*)d_in[20];
    const float* bc = (const float*)d_in[21];
    float* out = (float*)d_out;

    char* ws = (char*)d_ws;
    size_t off = 0;
    auto alloc = [&](size_t bytes) {
        void* p = ws + off;
        off += (bytes + 255) & ~(size_t)255;
        return p;
    };
    float* sqn = (float*)alloc(NPTS * 4);
    int* idx = (int*)alloc((size_t)NPTS * KNN * 4);
    float* x1 = (float*)alloc((size_t)NPTS * 64 * 4);
    float* x2 = (float*)alloc((size_t)NPTS * 64 * 4);
    float* x3 = (float*)alloc((size_t)NPTS * 128 * 4);
    float* x4 = (float*)alloc((size_t)NPTS * 256 * 4);
    float* outm = (float*)alloc((size_t)NPTS * 1024 * 4);
    float* gmax = (float*)alloc(NB * 1024 * 4);
    float* gmean = (float*)alloc(NB * 1024 * 4);
    float* ha = (float*)alloc(NB * 512 * 4);
    float* hb = (float*)alloc(NB * 256 * 4);
    (void)ws_size;

    // Dm and AB both alias outm: each is live only between its producer and
    // consumer within a layer (stream-ordered), and outm is written last.
    float* Dm = outm;
    float* AB = outm;

    dim3 dgrid(16, 16, 8);

    // layer 1 (C=3 -> 64)
    sqnorm_kernel<3><<<NPTS / 256, 256, 0, stream>>>(pos, sqn);
    dist_kernel<3><<<dgrid, 256, 0, stream>>>(pos, sqn, Dm);
    topk_kernel<<<NPTS / 4, 256, 0, stream>>>(Dm, idx);
    edge_gemm_kernel<3, 64><<<dim3(2, 128), 256, 0, stream>>>(pos, W1, b1, AB);
    gather_max_kernel<64><<<NPTS / 16, 256, 0, stream>>>(AB, idx, x1);

    // layer 2 (64 -> 64)
    sqnorm_kernel<64><<<NPTS / 256, 256, 0, stream>>>(x1, sqn);
    dist_kernel<64><<<dgrid, 256, 0, stream>>>(x1, sqn, Dm);
    topk_kernel<<<NPTS / 4, 256, 0, stream>>>(Dm, idx);
    edge_gemm_kernel<64, 64><<<dim3(2, 128), 256, 0, stream>>>(x1, W2, b2, AB);
    gather_max_kernel<64><<<NPTS / 16, 256, 0, stream>>>(AB, idx, x2);

    // layer 3 (64 -> 128)
    sqnorm_kernel<64><<<NPTS / 256, 256, 0, stream>>>(x2, sqn);
    dist_kernel<64><<<dgrid, 256, 0, stream>>>(x2, sqn, Dm);
    topk_kernel<<<NPTS / 4, 256, 0, stream>>>(Dm, idx);
    edge_gemm_kernel<64, 128><<<dim3(4, 128), 256, 0, stream>>>(x2, W3, b3, AB);
    gather_max_kernel<128><<<NPTS / 8, 256, 0, stream>>>(AB, idx, x3);

    // layer 4 (128 -> 256)
    sqnorm_kernel<128><<<NPTS / 256, 256, 0, stream>>>(x3, sqn);
    dist_kernel<128><<<dgrid, 256, 0, stream>>>(x3, sqn, Dm);
    topk_kernel<<<NPTS / 4, 256, 0, stream>>>(Dm, idx);
    edge_gemm_kernel<128, 256><<<dim3(8, 128), 256, 0, stream>>>(x3, W4, b4, AB);
    gather_max_kernel<256><<<NPTS / 4, 256, 0, stream>>>(AB, idx, x4);

    // cat @ Wm + bm   (overwrites Dm/AB/outm — safe, no longer needed)
    gemm_cat_kernel<<<NPTS / 8, 256, 0, stream>>>(x1, x2, x3, x4, Wm, bm, outm);

    // pooling
    pool_kernel<<<dim3(4, NB), 256, 0, stream>>>(outm, gmax, gmean);

    // head
    fc_a_kernel<<<16, 256, 0, stream>>>(gmax, gmean, Wa, ba, ha);
    bn_leaky_kernel<<<2, 256, 0, stream>>>(ha, ga, bea, 512);
    fc_b_kernel<<<8, 256, 0, stream>>>(ha, Wb, bb, hb);
    bn_leaky_kernel<<<1, 256, 0, stream>>>(hb, gb, beb, 256);
    fc_c_kernel<<<2, 256, 0, stream>>>(hb, Wc, bc, out);
}

// Round 4
// 645.591 us; speedup vs baseline: 3.5403x; 1.0865x over previous
//
#include <hip/hip_runtime.h>
#include <hip/hip_bf16.h>

#define NB 8
#define NP 1024
#define NPTS (NB * NP)
#define KNN 20

static __device__ __forceinline__ unsigned long long umin64(unsigned long long a,
                                                            unsigned long long b) {
    return a < b ? a : b;
}

// ---------------- distance matrix + folded sqnorm ----------------
// D[b][p][q] = sq[p]+sq[q]-2*dot(x_p,x_q). K-major LDS, float4 reads.
// Threads 0..63 own A-row sq, 64..127 own B-row sq (ascending-c accumulation,
// same FP order as a standalone sqnorm pass).
template <int C>
__global__ __launch_bounds__(256) void dist_kernel(const float* __restrict__ x,
                                                   float* __restrict__ Dm) {
    constexpr int BK = (C < 32) ? C : 32;
    const int b = blockIdx.z;
    const int p0 = blockIdx.y * 64;
    const int q0 = blockIdx.x * 64;
    const int tid = threadIdx.x;
    const int tx = tid & 15, ty = tid >> 4;
    const float* xb = x + (size_t)b * NP * C;

    __shared__ float sA[BK][68];
    __shared__ float sB[BK][68];
    __shared__ float sqa[64];
    __shared__ float sqb[64];

    float acc[4][4];
#pragma unroll
    for (int i = 0; i < 4; ++i)
#pragma unroll
        for (int j = 0; j < 4; ++j) acc[i][j] = 0.f;
    float sqreg = 0.f;

    for (int k0 = 0; k0 < C; k0 += BK) {
        if constexpr (C >= 32) {
#pragma unroll
            for (int u = 0; u < 2; ++u) {
                int v = tid + u * 256;  // [0,512)
                int m = v >> 3, c4 = (v & 7) * 4;
                float4 a = *(const float4*)&xb[(size_t)(p0 + m) * C + k0 + c4];
                sA[c4 + 0][m] = a.x;
                sA[c4 + 1][m] = a.y;
                sA[c4 + 2][m] = a.z;
                sA[c4 + 3][m] = a.w;
                float4 bb = *(const float4*)&xb[(size_t)(q0 + m) * C + k0 + c4];
                sB[c4 + 0][m] = bb.x;
                sB[c4 + 1][m] = bb.y;
                sB[c4 + 2][m] = bb.z;
                sB[c4 + 3][m] = bb.w;
            }
        } else {
            for (int t = tid; t < 64 * BK; t += 256) {
                int m = t / BK, c = t - m * BK;
                sA[c][m] = xb[(size_t)(p0 + m) * C + c];
                sB[c][m] = xb[(size_t)(q0 + m) * C + c];
            }
        }
        __syncthreads();

        if (tid < 64) {
#pragma unroll
            for (int c = 0; c < BK; ++c) sqreg += sA[c][tid] * sA[c][tid];
        } else if (tid < 128) {
#pragma unroll
            for (int c = 0; c < BK; ++c) sqreg += sB[c][tid - 64] * sB[c][tid - 64];
        }

#pragma unroll 8
        for (int c = 0; c < BK; ++c) {
            float4 a4 = *(const float4*)&sA[c][ty * 4];
            float4 b4 = *(const float4*)&sB[c][tx * 4];
            float av[4] = {a4.x, a4.y, a4.z, a4.w};
            float bv[4] = {b4.x, b4.y, b4.z, b4.w};
#pragma unroll
            for (int i = 0; i < 4; ++i)
#pragma unroll
                for (int j = 0; j < 4; ++j) acc[i][j] += av[i] * bv[j];
        }
        __syncthreads();
    }

    if (tid < 64) sqa[tid] = sqreg;
    else if (tid < 128) sqb[tid - 64] = sqreg;
    __syncthreads();

#pragma unroll
    for (int i = 0; i < 4; ++i) {
        int p = p0 + ty * 4 + i;
        float sqp = sqa[ty * 4 + i];
        float* drow = Dm + ((size_t)b * NP + p) * NP + q0;
#pragma unroll
        for (int j = 0; j < 4; ++j) {
            int q = tx * 4 + j;
            drow[q] = sqp + sqb[q] - 2.0f * acc[i][j];
        }
    }
}

// ---------------- top-20 per row, wave-local (no barriers, no LDS) ----------------
__global__ __launch_bounds__(256) void topk_kernel(const float* __restrict__ Dm,
                                                   int* __restrict__ idx) {
    const int w = threadIdx.x >> 6, lane = threadIdx.x & 63;
    const int p = blockIdx.x * 4 + w;
    const int b = p >> 10, pr = p & 1023;
    const float* row = Dm + ((size_t)b * NP + pr) * NP;

    unsigned long long k[16];
#pragma unroll
    for (int j = 0; j < 16; ++j) {
        int q = j * 64 + lane;
        float dv = row[q];
        unsigned u = __float_as_uint(dv);
        u = (u & 0x80000000u) ? ~u : (u | 0x80000000u);  // order-preserving map
        k[j] = ((unsigned long long)u << 32) | (unsigned)q;
    }

    for (int r = 0; r < KNN; ++r) {
        unsigned long long m = k[0];
#pragma unroll
        for (int j = 1; j < 16; ++j) m = umin64(m, k[j]);
#pragma unroll
        for (int s = 1; s < 64; s <<= 1) {
            unsigned long long o = __shfl_xor(m, s, 64);
            m = umin64(m, o);
        }
        if (lane == 0) idx[p * KNN + r] = (int)(m & 0xffffffffu);
#pragma unroll
        for (int j = 0; j < 16; ++j)
            if (k[j] == m) k[j] = ~0ull;
    }
}

// ---------------- EdgeConv as GEMM: AB[p, 0:Cout] = x_p.(W1-W2) + b ; AB[p, Cout:2Cout] = x_p.W2
// 64M x 128N tile, 4x8/thread, K-major LDS float4.
template <int Cin, int Cout>
__global__ __launch_bounds__(256) void edge_gemm_kernel(const float* __restrict__ x,
                                                        const float* __restrict__ W,
                                                        const float* __restrict__ bias,
                                                        float* __restrict__ AB) {
    constexpr int N2 = 2 * Cout;
    constexpr int BK = (Cin < 32) ? Cin : 32;
    const int n0 = blockIdx.x * 128;
    const int p0 = blockIdx.y * 64;
    const int tid = threadIdx.x;
    const int tx = tid & 15, ty = tid >> 4;

    __shared__ float sX[BK][68];
    __shared__ float sW[BK][132];

    float acc[4][8];
#pragma unroll
    for (int i = 0; i < 4; ++i)
#pragma unroll
        for (int j = 0; j < 8; ++j) acc[i][j] = 0.f;

    for (int k0 = 0; k0 < Cin; k0 += BK) {
        if constexpr (Cin >= 32) {
#pragma unroll
            for (int u = 0; u < 2; ++u) {
                int v = tid + u * 256;
                int m = v >> 3, c4 = (v & 7) * 4;
                float4 a = *(const float4*)&x[(size_t)(p0 + m) * Cin + k0 + c4];
                sX[c4 + 0][m] = a.x;
                sX[c4 + 1][m] = a.y;
                sX[c4 + 2][m] = a.z;
                sX[c4 + 3][m] = a.w;
            }
        } else {
            for (int t = tid; t < 64 * BK; t += 256) {
                int m = t / BK, c = t - m * BK;
                sX[c][m] = x[(size_t)(p0 + m) * Cin + c];
            }
        }
        for (int t = tid; t < BK * 128; t += 256) {
            int c = t >> 7, n = t & 127;
            int nn = n0 + n;
            float w;
            if (nn < Cout)
                w = W[(size_t)(k0 + c) * Cout + nn] - W[(size_t)(Cin + k0 + c) * Cout + nn];
            else
                w = W[(size_t)(Cin + k0 + c) * Cout + (nn - Cout)];
            sW[c][n] = w;
        }
        __syncthreads();

#pragma unroll 8
        for (int c = 0; c < BK; ++c) {
            float4 a4 = *(const float4*)&sX[c][ty * 4];
            float4 w0 = *(const float4*)&sW[c][tx * 4];
            float4 w1 = *(const float4*)&sW[c][64 + tx * 4];
            float av[4] = {a4.x, a4.y, a4.z, a4.w};
#pragma unroll
            for (int i = 0; i < 4; ++i) {
                acc[i][0] += av[i] * w0.x;
                acc[i][1] += av[i] * w0.y;
                acc[i][2] += av[i] * w0.z;
                acc[i][3] += av[i] * w0.w;
                acc[i][4] += av[i] * w1.x;
                acc[i][5] += av[i] * w1.y;
                acc[i][6] += av[i] * w1.z;
                acc[i][7] += av[i] * w1.w;
            }
        }
        __syncthreads();
    }

    const bool aH0 = (n0 < Cout);        // cols n0..n0+63 (Cout % 64 == 0)
    const bool aH1 = (n0 + 64 < Cout);   // cols n0+64..n0+127
    float4 z4 = {0.f, 0.f, 0.f, 0.f};
    float4 bb0 = aH0 ? *(const float4*)&bias[n0 + tx * 4] : z4;
    float4 bb1 = aH1 ? *(const float4*)&bias[n0 + 64 + tx * 4] : z4;

#pragma unroll
    for (int i = 0; i < 4; ++i) {
        float* orow = AB + (size_t)(p0 + ty * 4 + i) * N2 + n0;
        float4 o0, o1;
        o0.x = acc[i][0] + bb0.x;
        o0.y = acc[i][1] + bb0.y;
        o0.z = acc[i][2] + bb0.z;
        o0.w = acc[i][3] + bb0.w;
        o1.x = acc[i][4] + bb1.x;
        o1.y = acc[i][5] + bb1.y;
        o1.z = acc[i][6] + bb1.z;
        o1.w = acc[i][7] + bb1.w;
        *(float4*)&orow[tx * 4] = o0;
        *(float4*)&orow[64 + tx * 4] = o1;
    }
}

// ---------------- y[p,co] = A[p,co] + max_j Bv[base+idx[p,j], co] ----------------
template <int Cout>
__global__ __launch_bounds__(256) void gather_max_kernel(const float* __restrict__ AB,
                                                         const int* __restrict__ idx,
                                                         float* __restrict__ y) {
    constexpr int N2 = 2 * Cout;
    constexpr int TPP = Cout / 4;   // threads per point
    constexpr int PPB = 256 / TPP;  // points per block
    constexpr int RS = N2 / 4;      // AB row stride in float4
    const int pp = threadIdx.x / TPP;
    const int t = threadIdx.x % TPP;
    const int p = blockIdx.x * PPB + pp;
    const int base = p & ~(NP - 1);

    __shared__ int s_idx[PPB][KNN];
    for (int tt = threadIdx.x; tt < PPB * KNN; tt += 256) {
        int a = tt / KNN, r = tt - a * KNN;
        s_idx[a][r] = idx[(size_t)(blockIdx.x * PPB + a) * KNN + r];
    }
    __syncthreads();

    const float4* Brow = (const float4*)(AB + (size_t)base * N2 + Cout);

    int q0 = s_idx[pp][0];
    float4 m = Brow[(size_t)q0 * RS + t];
#pragma unroll
    for (int j = 1; j < KNN; ++j) {
        int q = s_idx[pp][j];
        float4 v = Brow[(size_t)q * RS + t];
        m.x = fmaxf(m.x, v.x);
        m.y = fmaxf(m.y, v.y);
        m.z = fmaxf(m.z, v.z);
        m.w = fmaxf(m.w, v.w);
    }
    float4 a = *(const float4*)(AB + (size_t)p * N2 + 4 * t);
    float4 o;
    o.x = a.x + m.x;
    o.y = a.y + m.y;
    o.z = a.z + m.z;
    o.w = a.w + m.w;
    *(float4*)(y + (size_t)p * Cout + 4 * t) = o;
}

// ---------------- cat(x1..x4) @ Wm + bm : [8192,512] x [512,1024] ----------------
// 64M x 128N tile, 4x8/thread, K-major LDS float4. K-chunks (32) never span
// source-array boundaries (64/128/256 are multiples of 32).
__global__ __launch_bounds__(256) void gemm_cat_kernel(const float* __restrict__ x1,
                                                       const float* __restrict__ x2,
                                                       const float* __restrict__ x3,
                                                       const float* __restrict__ x4,
                                                       const float* __restrict__ Wm,
                                                       const float* __restrict__ bm,
                                                       float* __restrict__ out) {
    const int n0 = blockIdx.x * 128;
    const int p0 = blockIdx.y * 64;
    const int tid = threadIdx.x;
    const int tx = tid & 15, ty = tid >> 4;

    __shared__ float sA[32][68];
    __shared__ float sW[32][132];

    float acc[4][8];
#pragma unroll
    for (int i = 0; i < 4; ++i)
#pragma unroll
        for (int j = 0; j < 8; ++j) acc[i][j] = 0.f;

    for (int k0 = 0; k0 < 512; k0 += 32) {
        const float* src;
        int cin, coff;
        if (k0 < 64) {
            src = x1; cin = 64; coff = k0;
        } else if (k0 < 128) {
            src = x2; cin = 64; coff = k0 - 64;
        } else if (k0 < 256) {
            src = x3; cin = 128; coff = k0 - 128;
        } else {
            src = x4; cin = 256; coff = k0 - 256;
        }
#pragma unroll
        for (int u = 0; u < 2; ++u) {
            int v = tid + u * 256;
            int m = v >> 3, c4 = (v & 7) * 4;
            float4 a = *(const float4*)&src[(size_t)(p0 + m) * cin + coff + c4];
            sA[c4 + 0][m] = a.x;
            sA[c4 + 1][m] = a.y;
            sA[c4 + 2][m] = a.z;
            sA[c4 + 3][m] = a.w;
        }
#pragma unroll
        for (int u = 0; u < 4; ++u) {
            int v = tid + u * 256;  // [0,1024)
            int c = v >> 5, n4 = (v & 31) * 4;
            *(float4*)&sW[c][n4] = *(const float4*)&Wm[(size_t)(k0 + c) * 1024 + n0 + n4];
        }
        __syncthreads();

#pragma unroll 8
        for (int c = 0; c < 32; ++c) {
            float4 a4 = *(const float4*)&sA[c][ty * 4];
            float4 w0 = *(const float4*)&sW[c][tx * 4];
            float4 w1 = *(const float4*)&sW[c][64 + tx * 4];
            float av[4] = {a4.x, a4.y, a4.z, a4.w};
#pragma unroll
            for (int i = 0; i < 4; ++i) {
                acc[i][0] += av[i] * w0.x;
                acc[i][1] += av[i] * w0.y;
                acc[i][2] += av[i] * w0.z;
                acc[i][3] += av[i] * w0.w;
                acc[i][4] += av[i] * w1.x;
                acc[i][5] += av[i] * w1.y;
                acc[i][6] += av[i] * w1.z;
                acc[i][7] += av[i] * w1.w;
            }
        }
        __syncthreads();
    }

    float4 bb0 = *(const float4*)&bm[n0 + tx * 4];
    float4 bb1 = *(const float4*)&bm[n0 + 64 + tx * 4];
#pragma unroll
    for (int i = 0; i < 4; ++i) {
        float* orow = out + (size_t)(p0 + ty * 4 + i) * 1024 + n0;
        float4 o0, o1;
        o0.x = acc[i][0] + bb0.x;
        o0.y = acc[i][1] + bb0.y;
        o0.z = acc[i][2] + bb0.z;
        o0.w = acc[i][3] + bb0.w;
        o1.x = acc[i][4] + bb1.x;
        o1.y = acc[i][5] + bb1.y;
        o1.z = acc[i][6] + bb1.z;
        o1.w = acc[i][7] + bb1.w;
        *(float4*)&orow[tx * 4] = o0;
        *(float4*)&orow[64 + tx * 4] = o1;
    }
}

// ---------------- global max+mean pool over P ----------------
__global__ __launch_bounds__(256) void pool_kernel(const float* __restrict__ out,
                                                   float* __restrict__ gmax,
                                                   float* __restrict__ gmean) {
    int b = blockIdx.y;
    int co = blockIdx.x * 256 + threadIdx.x;  // 0..1023
    const float* pb = out + (size_t)b * NP * 1024 + co;
    float m = -__builtin_inff(), s = 0.f;
    for (int p = 0; p < NP; ++p) {
        float v = pb[(size_t)p * 1024];
        m = fmaxf(m, v);
        s += v;
    }
    gmax[b * 1024 + co] = m;
    gmean[b * 1024 + co] = s * (1.0f / 1024.0f);
}

// ---------------- head ----------------
__global__ __launch_bounds__(256) void fc_a_kernel(const float* __restrict__ gmax,
                                                   const float* __restrict__ gmean,
                                                   const float* __restrict__ Wa,
                                                   const float* __restrict__ ba,
                                                   float* __restrict__ ha) {
    int t = blockIdx.x * 256 + threadIdx.x;  // 8*512
    if (t >= 8 * 512) return;
    int b = t >> 9, co = t & 511;
    float s = ba[co];
    for (int c = 0; c < 1024; ++c) s += gmax[b * 1024 + c] * Wa[c * 512 + co];
    for (int c = 0; c < 1024; ++c) s += gmean[b * 1024 + c] * Wa[(1024 + c) * 512 + co];
    ha[t] = s;
}

__global__ __launch_bounds__(256) void bn_leaky_kernel(float* __restrict__ h,
                                                       const float* __restrict__ g,
                                                       const float* __restrict__ be,
                                                       int ncol) {
    int co = blockIdx.x * 256 + threadIdx.x;
    if (co >= ncol) return;
    float mu = 0.f;
    for (int b = 0; b < NB; ++b) mu += h[b * ncol + co];
    mu *= 0.125f;
    float var = 0.f;
    for (int b = 0; b < NB; ++b) {
        float d = h[b * ncol + co] - mu;
        var += d * d;
    }
    var *= 0.125f;
    float inv = 1.0f / sqrtf(var + 1e-5f);
    for (int b = 0; b < NB; ++b) {
        float v = (h[b * ncol + co] - mu) * inv * g[co] + be[co];
        h[b * ncol + co] = v >= 0.f ? v : 0.2f * v;
    }
}

__global__ __launch_bounds__(256) void fc_b_kernel(const float* __restrict__ ha,
                                                   const float* __restrict__ Wb,
                                                   const float* __restrict__ bb,
                                                   float* __restrict__ hb) {
    int t = blockIdx.x * 256 + threadIdx.x;  // 8*256
    if (t >= 8 * 256) return;
    int b = t >> 8, co = t & 255;
    float s = bb[co];
    for (int c = 0; c < 512; ++c) s += ha[b * 512 + c] * Wb[c * 256 + co];
    hb[t] = s;
}

__global__ __launch_bounds__(256) void fc_c_kernel(const float* __restrict__ hb,
                                                   const float* __restrict__ Wc,
                                                   const float* __restrict__ bc,
                                                   float* __restrict__ outp) {
    int t = blockIdx.x * 256 + threadIdx.x;  // 8*40
    if (t >= 8 * 40) return;
    int b = t / 40, o = t - b * 40;
    float s = bc[o];
    for (int c = 0; c < 256; ++c) s += hb[b * 256 + c] * Wc[c * 40 + o];
    outp[t] = s;
}

extern "C" void kernel_launch(void* const* d_in, const int* in_sizes, int n_in,
                              void* d_out, int out_size, void* d_ws, size_t ws_size,
                              hipStream_t stream) {
    const float* pos = (const float*)d_in[0];
    const float* W1 = (const float*)d_in[2];
    const float* b1 = (const float*)d_in[3];
    const float* W2 = (const float*)d_in[4];
    const float* b2 = (const float*)d_in[5];
    const float* W3 = (const float*)d_in[6];
    const float* b3 = (const float*)d_in[7];
    const float* W4 = (const float*)d_in[8];
    const float* b4 = (const float*)d_in[9];
    const float* Wm = (const float*)d_in[10];
    const float* bm = (const float*)d_in[11];
    const float* Wa = (const float*)d_in[12];
    const float* ba = (const float*)d_in[13];
    const float* ga = (const float*)d_in[14];
    const float* bea = (const float*)d_in[15];
    const float* Wb = (const float*)d_in[16];
    const float* bb = (const float*)d_in[17];
    const float* gb = (const float*)d_in[18];
    const float* beb = (const float*)d_in[19];
    const float* Wc = (const float*)d_in[20];
    const float* bc = (const float*)d_in[21];
    float* out = (float*)d_out;

    char* ws = (char*)d_ws;
    size_t off = 0;
    auto alloc = [&](size_t bytes) {
        void* p = ws + off;
        off += (bytes + 255) & ~(size_t)255;
        return p;
    };
    int* idx = (int*)alloc((size_t)NPTS * KNN * 4);
    float* x1 = (float*)alloc((size_t)NPTS * 64 * 4);
    float* x2 = (float*)alloc((size_t)NPTS * 64 * 4);
    float* x3 = (float*)alloc((size_t)NPTS * 128 * 4);
    float* x4 = (float*)alloc((size_t)NPTS * 256 * 4);
    float* outm = (float*)alloc((size_t)NPTS * 1024 * 4);
    float* gmax = (float*)alloc(NB * 1024 * 4);
    float* gmean = (float*)alloc(NB * 1024 * 4);
    float* ha = (float*)alloc(NB * 512 * 4);
    float* hb = (float*)alloc(NB * 256 * 4);
    (void)ws_size;

    // Dm and AB both alias outm: each is live only between its producer and
    // consumer within a layer (stream-ordered), and outm is written last.
    float* Dm = outm;
    float* AB = outm;

    dim3 dgrid(16, 16, 8);

    // layer 1 (C=3 -> 64)
    dist_kernel<3><<<dgrid, 256, 0, stream>>>(pos, Dm);
    topk_kernel<<<NPTS / 4, 256, 0, stream>>>(Dm, idx);
    edge_gemm_kernel<3, 64><<<dim3(1, 128), 256, 0, stream>>>(pos, W1, b1, AB);
    gather_max_kernel<64><<<NPTS / 16, 256, 0, stream>>>(AB, idx, x1);

    // layer 2 (64 -> 64)
    dist_kernel<64><<<dgrid, 256, 0, stream>>>(x1, Dm);
    topk_kernel<<<NPTS / 4, 256, 0, stream>>>(Dm, idx);
    edge_gemm_kernel<64, 64><<<dim3(1, 128), 256, 0, stream>>>(x1, W2, b2, AB);
    gather_max_kernel<64><<<NPTS / 16, 256, 0, stream>>>(AB, idx, x2);

    // layer 3 (64 -> 128)
    dist_kernel<64><<<dgrid, 256, 0, stream>>>(x2, Dm);
    topk_kernel<<<NPTS / 4, 256, 0, stream>>>(Dm, idx);
    edge_gemm_kernel<64, 128><<<dim3(2, 128), 256, 0, stream>>>(x2, W3, b3, AB);
    gather_max_kernel<128><<<NPTS / 8, 256, 0, stream>>>(AB, idx, x3);

    // layer 4 (128 -> 256)
    dist_kernel<128><<<dgrid, 256, 0, stream>>>(x3, Dm);
    topk_kernel<<<NPTS / 4, 256, 0, stream>>>(Dm, idx);
    edge_gemm_kernel<128, 256><<<dim3(4, 128), 256, 0, stream>>>(x3, W4, b4, AB);
    gather_max_kernel<256><<<NPTS / 4, 256, 0, stream>>>(AB, idx, x4);

    // cat @ Wm + bm   (overwrites Dm/AB/outm — safe, no longer needed)
    gemm_cat_kernel<<<dim3(8, 128), 256, 0, stream>>>(x1, x2, x3, x4, Wm, bm, outm);

    // pooling
    pool_kernel<<<dim3(4, NB), 256, 0, stream>>>(outm, gmax, gmean);

    // head
    fc_a_kernel<<<16, 256, 0, stream>>>(gmax, gmean, Wa, ba, ha);
    bn_leaky_kernel<<<2, 256, 0, stream>>>(ha, ga, bea, 512);
    fc_b_kernel<<<8, 256, 0, stream>>>(ha, Wb, bb, hb);
    bn_leaky_kernel<<<1, 256, 0, stream>>>(hb, gb, beb, 256);
    fc_c_kernel<<<2, 256, 0, stream>>>(hb, Wc, bc, out);
}

// Round 5
// 500.362 us; speedup vs baseline: 4.5678x; 1.2902x over previous
//
#include <hip/hip_runtime.h>
#include <hip/hip_bf16.h>

#define NB 8
#define NP 1024
#define NPTS (NB * NP)
#define KNN 20

static __device__ __forceinline__ unsigned long long umin64(unsigned long long a,
                                                            unsigned long long b) {
    return a < b ? a : b;
}

// XOR swizzle for K-major transposed LDS tiles (stride 128 floats, no pad).
// Element (k, m): float4-group g=m>>2 stored at g^((k>>2)&7). Verified <=2-way banks.
static __device__ __forceinline__ int swz(int k, int m) {
    return ((((m >> 2) ^ ((k >> 2) & 7)) << 2) | (m & 3));
}

// ---------------- dist for C=3 (layer 1): 64x64 tile, scalar staging ----------------
__global__ __launch_bounds__(256) void dist3_kernel(const float* __restrict__ x,
                                                    float* __restrict__ Dm) {
    constexpr int C = 3;
    const int b = blockIdx.z;
    const int p0 = blockIdx.y * 64;
    const int q0 = blockIdx.x * 64;
    const int tid = threadIdx.x;
    const int tx = tid & 15, ty = tid >> 4;
    const float* xb = x + (size_t)b * NP * C;

    __shared__ float sA[C][68];
    __shared__ float sB[C][68];
    __shared__ float sqa[64];
    __shared__ float sqb[64];

    for (int t = tid; t < 64 * C; t += 256) {
        int m = t / C, c = t - m * C;
        sA[c][m] = xb[(size_t)(p0 + m) * C + c];
        sB[c][m] = xb[(size_t)(q0 + m) * C + c];
    }
    __syncthreads();

    if (tid < 64) {
        float s = 0.f;
#pragma unroll
        for (int c = 0; c < C; ++c) s += sA[c][tid] * sA[c][tid];
        sqa[tid] = s;
    } else if (tid < 128) {
        float s = 0.f;
#pragma unroll
        for (int c = 0; c < C; ++c) s += sB[c][tid - 64] * sB[c][tid - 64];
        sqb[tid - 64] = s;
    }

    float acc[4][4];
#pragma unroll
    for (int i = 0; i < 4; ++i)
#pragma unroll
        for (int j = 0; j < 4; ++j) acc[i][j] = 0.f;

#pragma unroll
    for (int c = 0; c < C; ++c) {
        float a4[4], b4[4];
#pragma unroll
        for (int i = 0; i < 4; ++i) a4[i] = sA[c][ty * 4 + i];
#pragma unroll
        for (int j = 0; j < 4; ++j) b4[j] = sB[c][tx * 4 + j];
#pragma unroll
        for (int i = 0; i < 4; ++i)
#pragma unroll
            for (int j = 0; j < 4; ++j) acc[i][j] += a4[i] * b4[j];
    }
    __syncthreads();

#pragma unroll
    for (int i = 0; i < 4; ++i) {
        int p = p0 + ty * 4 + i;
        float sqp = sqa[ty * 4 + i];
        float* drow = Dm + ((size_t)b * NP + p) * NP + q0;
#pragma unroll
        for (int j = 0; j < 4; ++j) {
            int q = tx * 4 + j;
            drow[q] = sqp + sqb[q] - 2.0f * acc[i][j];
        }
    }
}

// ---------------- dist for C>=32: 128x128 quadrant tile, 8x8/thread, swizzled LDS ----
template <int C>
__global__ __launch_bounds__(256, 2) void dist128_kernel(const float* __restrict__ x,
                                                         float* __restrict__ Dm) {
    const int b = blockIdx.z;
    const int p0 = blockIdx.y * 128;
    const int q0 = blockIdx.x * 128;
    const int tid = threadIdx.x;
    const int tx = tid & 15, ty = tid >> 4;
    const float* xb = x + (size_t)b * NP * C;

    __shared__ float sA[32][128];
    __shared__ float sB[32][128];
    __shared__ float sqa[128];
    __shared__ float sqb[128];

    float acc[8][8];
#pragma unroll
    for (int i = 0; i < 8; ++i)
#pragma unroll
        for (int j = 0; j < 8; ++j) acc[i][j] = 0.f;
    float sqreg = 0.f;

    for (int k0 = 0; k0 < C; k0 += 32) {
#pragma unroll
        for (int u = 0; u < 4; ++u) {
            int v = tid + u * 256;          // [0,1024)
            int m = v >> 3, c4 = (v & 7) * 4;
            float4 a = *(const float4*)&xb[(size_t)(p0 + m) * C + k0 + c4];
            sA[c4 + 0][swz(c4 + 0, m)] = a.x;
            sA[c4 + 1][swz(c4 + 1, m)] = a.y;
            sA[c4 + 2][swz(c4 + 2, m)] = a.z;
            sA[c4 + 3][swz(c4 + 3, m)] = a.w;
            float4 bb = *(const float4*)&xb[(size_t)(q0 + m) * C + k0 + c4];
            sB[c4 + 0][swz(c4 + 0, m)] = bb.x;
            sB[c4 + 1][swz(c4 + 1, m)] = bb.y;
            sB[c4 + 2][swz(c4 + 2, m)] = bb.z;
            sB[c4 + 3][swz(c4 + 3, m)] = bb.w;
        }
        __syncthreads();

        if (tid < 128) {
#pragma unroll 8
            for (int c = 0; c < 32; ++c) {
                float v = sA[c][swz(c, tid)];
                sqreg += v * v;
            }
        } else {
#pragma unroll 8
            for (int c = 0; c < 32; ++c) {
                float v = sB[c][swz(c, tid - 128)];
                sqreg += v * v;
            }
        }

#pragma unroll 4
        for (int c = 0; c < 32; ++c) {
            int xc = (c >> 2) & 7;
            int ga = ty ^ xc, gb = tx ^ xc;
            float4 a0 = *(const float4*)&sA[c][ga * 4];
            float4 a1 = *(const float4*)&sA[c][(16 + ga) * 4];
            float4 b0 = *(const float4*)&sB[c][gb * 4];
            float4 b1 = *(const float4*)&sB[c][(16 + gb) * 4];
            float av[8] = {a0.x, a0.y, a0.z, a0.w, a1.x, a1.y, a1.z, a1.w};
            float bv[8] = {b0.x, b0.y, b0.z, b0.w, b1.x, b1.y, b1.z, b1.w};
#pragma unroll
            for (int i = 0; i < 8; ++i)
#pragma unroll
                for (int j = 0; j < 8; ++j) acc[i][j] += av[i] * bv[j];
        }
        __syncthreads();
    }

    if (tid < 128) sqa[tid] = sqreg;
    else sqb[tid - 128] = sqreg;
    __syncthreads();

#pragma unroll
    for (int half = 0; half < 2; ++half) {
#pragma unroll
        for (int i = 0; i < 4; ++i) {
            int r = half * 64 + ty * 4 + i;
            float sp = sqa[r];
            float* drow = Dm + ((size_t)b * NP + p0 + r) * NP + q0;
            float4 o0, o1;
            o0.x = sp + sqb[tx * 4 + 0] - 2.0f * acc[half * 4 + i][0];
            o0.y = sp + sqb[tx * 4 + 1] - 2.0f * acc[half * 4 + i][1];
            o0.z = sp + sqb[tx * 4 + 2] - 2.0f * acc[half * 4 + i][2];
            o0.w = sp + sqb[tx * 4 + 3] - 2.0f * acc[half * 4 + i][3];
            o1.x = sp + sqb[64 + tx * 4 + 0] - 2.0f * acc[half * 4 + i][4];
            o1.y = sp + sqb[64 + tx * 4 + 1] - 2.0f * acc[half * 4 + i][5];
            o1.z = sp + sqb[64 + tx * 4 + 2] - 2.0f * acc[half * 4 + i][6];
            o1.w = sp + sqb[64 + tx * 4 + 3] - 2.0f * acc[half * 4 + i][7];
            *(float4*)&drow[tx * 4] = o0;
            *(float4*)&drow[64 + tx * 4] = o1;
        }
    }
}

// ---------------- top-20 per row, wave-local ----------------
__global__ __launch_bounds__(256) void topk_kernel(const float* __restrict__ Dm,
                                                   int* __restrict__ idx) {
    const int w = threadIdx.x >> 6, lane = threadIdx.x & 63;
    const int p = blockIdx.x * 4 + w;
    const int b = p >> 10, pr = p & 1023;
    const float* row = Dm + ((size_t)b * NP + pr) * NP;

    unsigned long long k[16];
#pragma unroll
    for (int j = 0; j < 16; ++j) {
        int q = j * 64 + lane;
        float dv = row[q];
        unsigned u = __float_as_uint(dv);
        u = (u & 0x80000000u) ? ~u : (u | 0x80000000u);
        k[j] = ((unsigned long long)u << 32) | (unsigned)q;
    }

    for (int r = 0; r < KNN; ++r) {
        unsigned long long m = k[0];
#pragma unroll
        for (int j = 1; j < 16; ++j) m = umin64(m, k[j]);
#pragma unroll
        for (int s = 1; s < 64; s <<= 1) {
            unsigned long long o = __shfl_xor(m, s, 64);
            m = umin64(m, o);
        }
        if (lane == 0) idx[p * KNN + r] = (int)(m & 0xffffffffu);
#pragma unroll
        for (int j = 0; j < 16; ++j)
            if (k[j] == m) k[j] = ~0ull;
    }
}

// ---------------- EdgeConv as GEMM ----------------
template <int Cin, int Cout>
__global__ __launch_bounds__(256) void edge_gemm_kernel(const float* __restrict__ x,
                                                        const float* __restrict__ W,
                                                        const float* __restrict__ bias,
                                                        float* __restrict__ AB) {
    constexpr int N2 = 2 * Cout;
    constexpr int BK = (Cin < 32) ? Cin : 32;
    const int n0 = blockIdx.x * 128;
    const int p0 = blockIdx.y * 64;
    const int tid = threadIdx.x;
    const int tx = tid & 15, ty = tid >> 4;

    __shared__ float sX[BK][68];
    __shared__ float sW[BK][132];

    float acc[4][8];
#pragma unroll
    for (int i = 0; i < 4; ++i)
#pragma unroll
        for (int j = 0; j < 8; ++j) acc[i][j] = 0.f;

    for (int k0 = 0; k0 < Cin; k0 += BK) {
        if constexpr (Cin >= 32) {
#pragma unroll
            for (int u = 0; u < 2; ++u) {
                int v = tid + u * 256;
                int m = v >> 3, c4 = (v & 7) * 4;
                float4 a = *(const float4*)&x[(size_t)(p0 + m) * Cin + k0 + c4];
                sX[c4 + 0][m] = a.x;
                sX[c4 + 1][m] = a.y;
                sX[c4 + 2][m] = a.z;
                sX[c4 + 3][m] = a.w;
            }
        } else {
            for (int t = tid; t < 64 * BK; t += 256) {
                int m = t / BK, c = t - m * BK;
                sX[c][m] = x[(size_t)(p0 + m) * Cin + c];
            }
        }
        for (int t = tid; t < BK * 128; t += 256) {
            int c = t >> 7, n = t & 127;
            int nn = n0 + n;
            float w;
            if (nn < Cout)
                w = W[(size_t)(k0 + c) * Cout + nn] - W[(size_t)(Cin + k0 + c) * Cout + nn];
            else
                w = W[(size_t)(Cin + k0 + c) * Cout + (nn - Cout)];
            sW[c][n] = w;
        }
        __syncthreads();

#pragma unroll 8
        for (int c = 0; c < BK; ++c) {
            float4 a4 = *(const float4*)&sX[c][ty * 4];
            float4 w0 = *(const float4*)&sW[c][tx * 4];
            float4 w1 = *(const float4*)&sW[c][64 + tx * 4];
            float av[4] = {a4.x, a4.y, a4.z, a4.w};
#pragma unroll
            for (int i = 0; i < 4; ++i) {
                acc[i][0] += av[i] * w0.x;
                acc[i][1] += av[i] * w0.y;
                acc[i][2] += av[i] * w0.z;
                acc[i][3] += av[i] * w0.w;
                acc[i][4] += av[i] * w1.x;
                acc[i][5] += av[i] * w1.y;
                acc[i][6] += av[i] * w1.z;
                acc[i][7] += av[i] * w1.w;
            }
        }
        __syncthreads();
    }

    const bool aH0 = (n0 < Cout);
    const bool aH1 = (n0 + 64 < Cout);
    float4 z4 = {0.f, 0.f, 0.f, 0.f};
    float4 bb0 = aH0 ? *(const float4*)&bias[n0 + tx * 4] : z4;
    float4 bb1 = aH1 ? *(const float4*)&bias[n0 + 64 + tx * 4] : z4;

#pragma unroll
    for (int i = 0; i < 4; ++i) {
        float* orow = AB + (size_t)(p0 + ty * 4 + i) * N2 + n0;
        float4 o0, o1;
        o0.x = acc[i][0] + bb0.x;
        o0.y = acc[i][1] + bb0.y;
        o0.z = acc[i][2] + bb0.z;
        o0.w = acc[i][3] + bb0.w;
        o1.x = acc[i][4] + bb1.x;
        o1.y = acc[i][5] + bb1.y;
        o1.z = acc[i][6] + bb1.z;
        o1.w = acc[i][7] + bb1.w;
        *(float4*)&orow[tx * 4] = o0;
        *(float4*)&orow[64 + tx * 4] = o1;
    }
}

// ---------------- gather-max ----------------
template <int Cout>
__global__ __launch_bounds__(256) void gather_max_kernel(const float* __restrict__ AB,
                                                         const int* __restrict__ idx,
                                                         float* __restrict__ y) {
    constexpr int N2 = 2 * Cout;
    constexpr int TPP = Cout / 4;
    constexpr int PPB = 256 / TPP;
    constexpr int RS = N2 / 4;
    const int pp = threadIdx.x / TPP;
    const int t = threadIdx.x % TPP;
    const int p = blockIdx.x * PPB + pp;
    const int base = p & ~(NP - 1);

    __shared__ int s_idx[PPB][KNN];
    for (int tt = threadIdx.x; tt < PPB * KNN; tt += 256) {
        int a = tt / KNN, r = tt - a * KNN;
        s_idx[a][r] = idx[(size_t)(blockIdx.x * PPB + a) * KNN + r];
    }
    __syncthreads();

    const float4* Brow = (const float4*)(AB + (size_t)base * N2 + Cout);

    int q0 = s_idx[pp][0];
    float4 m = Brow[(size_t)q0 * RS + t];
#pragma unroll
    for (int j = 1; j < KNN; ++j) {
        int q = s_idx[pp][j];
        float4 v = Brow[(size_t)q * RS + t];
        m.x = fmaxf(m.x, v.x);
        m.y = fmaxf(m.y, v.y);
        m.z = fmaxf(m.z, v.z);
        m.w = fmaxf(m.w, v.w);
    }
    float4 a = *(const float4*)(AB + (size_t)p * N2 + 4 * t);
    float4 o;
    o.x = a.x + m.x;
    o.y = a.y + m.y;
    o.z = a.z + m.z;
    o.w = a.w + m.w;
    *(float4*)(y + (size_t)p * Cout + 4 * t) = o;
}

// ---------------- cat(x1..x4) @ Wm + bm : 128x128 quadrant tile, 8x8/thread ----------
__global__ __launch_bounds__(256, 2) void gemm_cat_kernel(const float* __restrict__ x1,
                                                          const float* __restrict__ x2,
                                                          const float* __restrict__ x3,
                                                          const float* __restrict__ x4,
                                                          const float* __restrict__ Wm,
                                                          const float* __restrict__ bm,
                                                          float* __restrict__ out) {
    const int n0 = blockIdx.x * 128;
    const int p0 = blockIdx.y * 128;
    const int tid = threadIdx.x;
    const int tx = tid & 15, ty = tid >> 4;

    __shared__ float sA[32][128];   // swizzled (transpose scatter)
    __shared__ float sW[32][132];   // padded, natural layout

    float acc[8][8];
#pragma unroll
    for (int i = 0; i < 8; ++i)
#pragma unroll
        for (int j = 0; j < 8; ++j) acc[i][j] = 0.f;

    for (int k0 = 0; k0 < 512; k0 += 32) {
        const float* src;
        int cin, coff;
        if (k0 < 64) {
            src = x1; cin = 64; coff = k0;
        } else if (k0 < 128) {
            src = x2; cin = 64; coff = k0 - 64;
        } else if (k0 < 256) {
            src = x3; cin = 128; coff = k0 - 128;
        } else {
            src = x4; cin = 256; coff = k0 - 256;
        }
#pragma unroll
        for (int u = 0; u < 4; ++u) {
            int v = tid + u * 256;  // [0,1024)
            int m = v >> 3, c4 = (v & 7) * 4;
            float4 a = *(const float4*)&src[(size_t)(p0 + m) * cin + coff + c4];
            sA[c4 + 0][swz(c4 + 0, m)] = a.x;
            sA[c4 + 1][swz(c4 + 1, m)] = a.y;
            sA[c4 + 2][swz(c4 + 2, m)] = a.z;
            sA[c4 + 3][swz(c4 + 3, m)] = a.w;
        }
#pragma unroll
        for (int u = 0; u < 4; ++u) {
            int v = tid + u * 256;  // [0,1024)
            int c = v >> 5, n4 = (v & 31) * 4;
            *(float4*)&sW[c][n4] = *(const float4*)&Wm[(size_t)(k0 + c) * 1024 + n0 + n4];
        }
        __syncthreads();

#pragma unroll 4
        for (int c = 0; c < 32; ++c) {
            int xc = (c >> 2) & 7;
            int ga = ty ^ xc;
            float4 a0 = *(const float4*)&sA[c][ga * 4];
            float4 a1 = *(const float4*)&sA[c][(16 + ga) * 4];
            float4 w0 = *(const float4*)&sW[c][tx * 4];
            float4 w1 = *(const float4*)&sW[c][64 + tx * 4];
            float av[8] = {a0.x, a0.y, a0.z, a0.w, a1.x, a1.y, a1.z, a1.w};
            float wv[8] = {w0.x, w0.y, w0.z, w0.w, w1.x, w1.y, w1.z, w1.w};
#pragma unroll
            for (int i = 0; i < 8; ++i)
#pragma unroll
                for (int j = 0; j < 8; ++j) acc[i][j] += av[i] * wv[j];
        }
        __syncthreads();
    }

    float4 bb0 = *(const float4*)&bm[n0 + tx * 4];
    float4 bb1 = *(const float4*)&bm[n0 + 64 + tx * 4];
#pragma unroll
    for (int half = 0; half < 2; ++half) {
#pragma unroll
        for (int i = 0; i < 4; ++i) {
            float* orow = out + (size_t)(p0 + half * 64 + ty * 4 + i) * 1024 + n0;
            float4 o0, o1;
            o0.x = acc[half * 4 + i][0] + bb0.x;
            o0.y = acc[half * 4 + i][1] + bb0.y;
            o0.z = acc[half * 4 + i][2] + bb0.z;
            o0.w = acc[half * 4 + i][3] + bb0.w;
            o1.x = acc[half * 4 + i][4] + bb1.x;
            o1.y = acc[half * 4 + i][5] + bb1.y;
            o1.z = acc[half * 4 + i][6] + bb1.z;
            o1.w = acc[half * 4 + i][7] + bb1.w;
            *(float4*)&orow[tx * 4] = o0;
            *(float4*)&orow[64 + tx * 4] = o1;
        }
    }
}

// ---------------- partial max+mean pool (P split 4-way) ----------------
__global__ __launch_bounds__(256) void pool_part_kernel(const float* __restrict__ outm,
                                                        float* __restrict__ pmax,
                                                        float* __restrict__ psum) {
    int co = blockIdx.x * 256 + threadIdx.x;  // 0..1023
    int b = blockIdx.y;
    int z = blockIdx.z;
    const float* pb = outm + (size_t)b * NP * 1024 + (size_t)z * 256 * 1024 + co;
    float m = -__builtin_inff(), s = 0.f;
    for (int p = 0; p < 256; ++p) {
        float v = pb[(size_t)p * 1024];
        m = fmaxf(m, v);
        s += v;
    }
    pmax[(size_t)(z * NB + b) * 1024 + co] = m;
    psum[(size_t)(z * NB + b) * 1024 + co] = s;
}

// ---------------- fc_a: [8,2048]x[2048,512], K-split 16, combines pool partials ------
__global__ __launch_bounds__(256) void fc_a_kernel(const float* __restrict__ pmax,
                                                   const float* __restrict__ psum,
                                                   const float* __restrict__ Wa,
                                                   const float* __restrict__ ba,
                                                   float* __restrict__ ha) {
    const int b = blockIdx.y;
    const int n0 = blockIdx.x * 64;
    const int tid = threadIdx.x;
    __shared__ float gm[2048];
    __shared__ float4 part[16][16];

    for (int c = tid; c < 1024; c += 256) {
        float m = pmax[(size_t)b * 1024 + c];
        float s = psum[(size_t)b * 1024 + c];
#pragma unroll
        for (int z = 1; z < 4; ++z) {
            m = fmaxf(m, pmax[(size_t)(z * NB + b) * 1024 + c]);
            s += psum[(size_t)(z * NB + b) * 1024 + c];
        }
        gm[c] = m;
        gm[1024 + c] = s * (1.0f / 1024.0f);
    }
    __syncthreads();

    const int cg = tid & 15, kp = tid >> 4;
    const int co = n0 + cg * 4;
    float4 acc = {0.f, 0.f, 0.f, 0.f};
    const float* Wp = Wa + (size_t)(kp * 128) * 512 + co;
    const float* gp = gm + kp * 128;
#pragma unroll 8
    for (int k = 0; k < 128; ++k) {
        float g = gp[k];
        float4 w = *(const float4*)&Wp[(size_t)k * 512];
        acc.x += g * w.x;
        acc.y += g * w.y;
        acc.z += g * w.z;
        acc.w += g * w.w;
    }
    part[kp][cg] = acc;
    __syncthreads();
    if (tid < 16) {
        float4 s = part[0][tid];
#pragma unroll
        for (int z = 1; z < 16; ++z) {
            float4 p = part[z][tid];
            s.x += p.x; s.y += p.y; s.z += p.z; s.w += p.w;
        }
        float4 bb = *(const float4*)&ba[n0 + tid * 4];
        s.x += bb.x; s.y += bb.y; s.z += bb.z; s.w += bb.w;
        *(float4*)&ha[(size_t)b * 512 + n0 + tid * 4] = s;
    }
}

__global__ __launch_bounds__(256) void bn_leaky_kernel(float* __restrict__ h,
                                                       const float* __restrict__ g,
                                                       const float* __restrict__ be,
                                                       int ncol) {
    int co = blockIdx.x * 256 + threadIdx.x;
    if (co >= ncol) return;
    float mu = 0.f;
    for (int b = 0; b < NB; ++b) mu += h[b * ncol + co];
    mu *= 0.125f;
    float var = 0.f;
    for (int b = 0; b < NB; ++b) {
        float d = h[b * ncol + co] - mu;
        var += d * d;
    }
    var *= 0.125f;
    float inv = 1.0f / sqrtf(var + 1e-5f);
    for (int b = 0; b < NB; ++b) {
        float v = (h[b * ncol + co] - mu) * inv * g[co] + be[co];
        h[b * ncol + co] = v >= 0.f ? v : 0.2f * v;
    }
}

// ---------------- fc_b: [8,512]x[512,256], K-split 16 ----------------
__global__ __launch_bounds__(256) void fc_b_kernel(const float* __restrict__ ha,
                                                   const float* __restrict__ Wb,
                                                   const float* __restrict__ bb,
                                                   float* __restrict__ hb) {
    const int b = blockIdx.y;
    const int n0 = blockIdx.x * 64;
    const int tid = threadIdx.x;
    __shared__ float sh[512];
    __shared__ float4 part[16][16];

    for (int c = tid; c < 512; c += 256) sh[c] = ha[(size_t)b * 512 + c];
    __syncthreads();

    const int cg = tid & 15, kp = tid >> 4;
    const int co = n0 + cg * 4;
    float4 acc = {0.f, 0.f, 0.f, 0.f};
#pragma unroll 8
    for (int k = 0; k < 32; ++k) {
        float g = sh[kp * 32 + k];
        float4 w = *(const float4*)&Wb[(size_t)(kp * 32 + k) * 256 + co];
        acc.x += g * w.x;
        acc.y += g * w.y;
        acc.z += g * w.z;
        acc.w += g * w.w;
    }
    part[kp][cg] = acc;
    __syncthreads();
    if (tid < 16) {
        float4 s = part[0][tid];
#pragma unroll
        for (int z = 1; z < 16; ++z) {
            float4 p = part[z][tid];
            s.x += p.x; s.y += p.y; s.z += p.z; s.w += p.w;
        }
        float4 bv = *(const float4*)&bb[n0 + tid * 4];
        s.x += bv.x; s.y += bv.y; s.z += bv.z; s.w += bv.w;
        *(float4*)&hb[(size_t)b * 256 + n0 + tid * 4] = s;
    }
}

__global__ __launch_bounds__(256) void fc_c_kernel(const float* __restrict__ hb,
                                                   const float* __restrict__ Wc,
                                                   const float* __restrict__ bc,
                                                   float* __restrict__ outp) {
    int t = blockIdx.x * 256 + threadIdx.x;  // 8*40
    if (t >= 8 * 40) return;
    int b = t / 40, o = t - b * 40;
    float s = bc[o];
    for (int c = 0; c < 256; ++c) s += hb[b * 256 + c] * Wc[c * 40 + o];
    outp[t] = s;
}

extern "C" void kernel_launch(void* const* d_in, const int* in_sizes, int n_in,
                              void* d_out, int out_size, void* d_ws, size_t ws_size,
                              hipStream_t stream) {
    const float* pos = (const float*)d_in[0];
    const float* W1 = (const float*)d_in[2];
    const float* b1 = (const float*)d_in[3];
    const float* W2 = (const float*)d_in[4];
    const float* b2 = (const float*)d_in[5];
    const float* W3 = (const float*)d_in[6];
    const float* b3 = (const float*)d_in[7];
    const float* W4 = (const float*)d_in[8];
    const float* b4 = (const float*)d_in[9];
    const float* Wm = (const float*)d_in[10];
    const float* bm = (const float*)d_in[11];
    const float* Wa = (const float*)d_in[12];
    const float* ba = (const float*)d_in[13];
    const float* ga = (const float*)d_in[14];
    const float* bea = (const float*)d_in[15];
    const float* Wb = (const float*)d_in[16];
    const float* bb = (const float*)d_in[17];
    const float* gb = (const float*)d_in[18];
    const float* beb = (const float*)d_in[19];
    const float* Wc = (const float*)d_in[20];
    const float* bc = (const float*)d_in[21];
    float* out = (float*)d_out;

    char* ws = (char*)d_ws;
    size_t off = 0;
    auto alloc = [&](size_t bytes) {
        void* p = ws + off;
        off += (bytes + 255) & ~(size_t)255;
        return p;
    };
    int* idx = (int*)alloc((size_t)NPTS * KNN * 4);
    float* x1 = (float*)alloc((size_t)NPTS * 64 * 4);
    float* x2 = (float*)alloc((size_t)NPTS * 64 * 4);
    float* x3 = (float*)alloc((size_t)NPTS * 128 * 4);
    float* x4 = (float*)alloc((size_t)NPTS * 256 * 4);
    float* outm = (float*)alloc((size_t)NPTS * 1024 * 4);
    float* pmax = (float*)alloc((size_t)4 * NB * 1024 * 4);
    float* psum = (float*)alloc((size_t)4 * NB * 1024 * 4);
    float* ha = (float*)alloc(NB * 512 * 4);
    float* hb = (float*)alloc(NB * 256 * 4);
    (void)ws_size;

    // Dm and AB alias outm (live only within a layer, stream-ordered).
    float* Dm = outm;
    float* AB = outm;

    dim3 dgrid128(8, 8, 8);

    // layer 1 (C=3 -> 64)
    dist3_kernel<<<dim3(16, 16, 8), 256, 0, stream>>>(pos, Dm);
    topk_kernel<<<NPTS / 4, 256, 0, stream>>>(Dm, idx);
    edge_gemm_kernel<3, 64><<<dim3(1, 128), 256, 0, stream>>>(pos, W1, b1, AB);
    gather_max_kernel<64><<<NPTS / 16, 256, 0, stream>>>(AB, idx, x1);

    // layer 2 (64 -> 64)
    dist128_kernel<64><<<dgrid128, 256, 0, stream>>>(x1, Dm);
    topk_kernel<<<NPTS / 4, 256, 0, stream>>>(Dm, idx);
    edge_gemm_kernel<64, 64><<<dim3(1, 128), 256, 0, stream>>>(x1, W2, b2, AB);
    gather_max_kernel<64><<<NPTS / 16, 256, 0, stream>>>(AB, idx, x2);

    // layer 3 (64 -> 128)
    dist128_kernel<64><<<dgrid128, 256, 0, stream>>>(x2, Dm);
    topk_kernel<<<NPTS / 4, 256, 0, stream>>>(Dm, idx);
    edge_gemm_kernel<64, 128><<<dim3(2, 128), 256, 0, stream>>>(x2, W3, b3, AB);
    gather_max_kernel<128><<<NPTS / 8, 256, 0, stream>>>(AB, idx, x3);

    // layer 4 (128 -> 256)
    dist128_kernel<128><<<dgrid128, 256, 0, stream>>>(x3, Dm);
    topk_kernel<<<NPTS / 4, 256, 0, stream>>>(Dm, idx);
    edge_gemm_kernel<128, 256><<<dim3(4, 128), 256, 0, stream>>>(x3, W4, b4, AB);
    gather_max_kernel<256><<<NPTS / 4, 256, 0, stream>>>(AB, idx, x4);

    // cat @ Wm + bm   (overwrites Dm/AB/outm — safe)
    gemm_cat_kernel<<<dim3(8, 64), 256, 0, stream>>>(x1, x2, x3, x4, Wm, bm, outm);

    // pooling partials + head
    pool_part_kernel<<<dim3(4, NB, 4), 256, 0, stream>>>(outm, pmax, psum);
    fc_a_kernel<<<dim3(8, NB), 256, 0, stream>>>(pmax, psum, Wa, ba, ha);
    bn_leaky_kernel<<<2, 256, 0, stream>>>(ha, ga, bea, 512);
    fc_b_kernel<<<dim3(4, NB), 256, 0, stream>>>(ha, Wb, bb, hb);
    bn_leaky_kernel<<<1, 256, 0, stream>>>(hb, gb, beb, 256);
    fc_c_kernel<<<2, 256, 0, stream>>>(hb, Wc, bc, out);
}

// Round 6
// 474.403 us; speedup vs baseline: 4.8178x; 1.0547x over previous
//
#include <hip/hip_runtime.h>
#include <hip/hip_bf16.h>

#define NB 8
#define NP 1024
#define NPTS (NB * NP)
#define KNN 20

static __device__ __forceinline__ unsigned long long umin64(unsigned long long a,
                                                            unsigned long long b) {
    return a < b ? a : b;
}

// XOR swizzle for K-major transposed LDS tiles (stride 128 floats, no pad).
static __device__ __forceinline__ int swz(int k, int m) {
    return ((((m >> 2) ^ ((k >> 2) & 7)) << 2) | (m & 3));
}

// ---------------- dist for C=3 (layer 1) ----------------
__global__ __launch_bounds__(256) void dist3_kernel(const float* __restrict__ x,
                                                    float* __restrict__ Dm) {
    constexpr int C = 3;
    const int b = blockIdx.z;
    const int p0 = blockIdx.y * 64;
    const int q0 = blockIdx.x * 64;
    const int tid = threadIdx.x;
    const int tx = tid & 15, ty = tid >> 4;
    const float* xb = x + (size_t)b * NP * C;

    __shared__ float sA[C][68];
    __shared__ float sB[C][68];
    __shared__ float sqa[64];
    __shared__ float sqb[64];

    for (int t = tid; t < 64 * C; t += 256) {
        int m = t / C, c = t - m * C;
        sA[c][m] = xb[(size_t)(p0 + m) * C + c];
        sB[c][m] = xb[(size_t)(q0 + m) * C + c];
    }
    __syncthreads();

    if (tid < 64) {
        float s = 0.f;
#pragma unroll
        for (int c = 0; c < C; ++c) s += sA[c][tid] * sA[c][tid];
        sqa[tid] = s;
    } else if (tid < 128) {
        float s = 0.f;
#pragma unroll
        for (int c = 0; c < C; ++c) s += sB[c][tid - 64] * sB[c][tid - 64];
        sqb[tid - 64] = s;
    }

    float acc[4][4];
#pragma unroll
    for (int i = 0; i < 4; ++i)
#pragma unroll
        for (int j = 0; j < 4; ++j) acc[i][j] = 0.f;

#pragma unroll
    for (int c = 0; c < C; ++c) {
        float a4[4], b4[4];
#pragma unroll
        for (int i = 0; i < 4; ++i) a4[i] = sA[c][ty * 4 + i];
#pragma unroll
        for (int j = 0; j < 4; ++j) b4[j] = sB[c][tx * 4 + j];
#pragma unroll
        for (int i = 0; i < 4; ++i)
#pragma unroll
            for (int j = 0; j < 4; ++j) acc[i][j] += a4[i] * b4[j];
    }
    __syncthreads();

#pragma unroll
    for (int i = 0; i < 4; ++i) {
        int p = p0 + ty * 4 + i;
        float sqp = sqa[ty * 4 + i];
        float* drow = Dm + ((size_t)b * NP + p) * NP + q0;
#pragma unroll
        for (int j = 0; j < 4; ++j) {
            int q = tx * 4 + j;
            drow[q] = sqp + sqb[q] - 2.0f * acc[i][j];
        }
    }
}

// ---------------- dist for C>=32: 128x128 quadrant tile, 8x8/thread ----------------
template <int C>
__global__ __launch_bounds__(256, 2) void dist128_kernel(const float* __restrict__ x,
                                                         float* __restrict__ Dm) {
    const int b = blockIdx.z;
    const int p0 = blockIdx.y * 128;
    const int q0 = blockIdx.x * 128;
    const int tid = threadIdx.x;
    const int tx = tid & 15, ty = tid >> 4;
    const float* xb = x + (size_t)b * NP * C;

    __shared__ float sA[32][128];
    __shared__ float sB[32][128];
    __shared__ float sqa[128];
    __shared__ float sqb[128];

    float acc[8][8];
#pragma unroll
    for (int i = 0; i < 8; ++i)
#pragma unroll
        for (int j = 0; j < 8; ++j) acc[i][j] = 0.f;
    float sqreg = 0.f;

    for (int k0 = 0; k0 < C; k0 += 32) {
#pragma unroll
        for (int u = 0; u < 4; ++u) {
            int v = tid + u * 256;
            int m = v >> 3, c4 = (v & 7) * 4;
            float4 a = *(const float4*)&xb[(size_t)(p0 + m) * C + k0 + c4];
            sA[c4 + 0][swz(c4 + 0, m)] = a.x;
            sA[c4 + 1][swz(c4 + 1, m)] = a.y;
            sA[c4 + 2][swz(c4 + 2, m)] = a.z;
            sA[c4 + 3][swz(c4 + 3, m)] = a.w;
            float4 bb = *(const float4*)&xb[(size_t)(q0 + m) * C + k0 + c4];
            sB[c4 + 0][swz(c4 + 0, m)] = bb.x;
            sB[c4 + 1][swz(c4 + 1, m)] = bb.y;
            sB[c4 + 2][swz(c4 + 2, m)] = bb.z;
            sB[c4 + 3][swz(c4 + 3, m)] = bb.w;
        }
        __syncthreads();

        if (tid < 128) {
#pragma unroll 8
            for (int c = 0; c < 32; ++c) {
                float v = sA[c][swz(c, tid)];
                sqreg += v * v;
            }
        } else {
#pragma unroll 8
            for (int c = 0; c < 32; ++c) {
                float v = sB[c][swz(c, tid - 128)];
                sqreg += v * v;
            }
        }

#pragma unroll 4
        for (int c = 0; c < 32; ++c) {
            int xc = (c >> 2) & 7;
            int ga = ty ^ xc, gb = tx ^ xc;
            float4 a0 = *(const float4*)&sA[c][ga * 4];
            float4 a1 = *(const float4*)&sA[c][(16 + ga) * 4];
            float4 b0 = *(const float4*)&sB[c][gb * 4];
            float4 b1 = *(const float4*)&sB[c][(16 + gb) * 4];
            float av[8] = {a0.x, a0.y, a0.z, a0.w, a1.x, a1.y, a1.z, a1.w};
            float bv[8] = {b0.x, b0.y, b0.z, b0.w, b1.x, b1.y, b1.z, b1.w};
#pragma unroll
            for (int i = 0; i < 8; ++i)
#pragma unroll
                for (int j = 0; j < 8; ++j) acc[i][j] += av[i] * bv[j];
        }
        __syncthreads();
    }

    if (tid < 128) sqa[tid] = sqreg;
    else sqb[tid - 128] = sqreg;
    __syncthreads();

#pragma unroll
    for (int half = 0; half < 2; ++half) {
#pragma unroll
        for (int i = 0; i < 4; ++i) {
            int r = half * 64 + ty * 4 + i;
            float sp = sqa[r];
            float* drow = Dm + ((size_t)b * NP + p0 + r) * NP + q0;
            float4 o0, o1;
            o0.x = sp + sqb[tx * 4 + 0] - 2.0f * acc[half * 4 + i][0];
            o0.y = sp + sqb[tx * 4 + 1] - 2.0f * acc[half * 4 + i][1];
            o0.z = sp + sqb[tx * 4 + 2] - 2.0f * acc[half * 4 + i][2];
            o0.w = sp + sqb[tx * 4 + 3] - 2.0f * acc[half * 4 + i][3];
            o1.x = sp + sqb[64 + tx * 4 + 0] - 2.0f * acc[half * 4 + i][4];
            o1.y = sp + sqb[64 + tx * 4 + 1] - 2.0f * acc[half * 4 + i][5];
            o1.z = sp + sqb[64 + tx * 4 + 2] - 2.0f * acc[half * 4 + i][6];
            o1.w = sp + sqb[64 + tx * 4 + 3] - 2.0f * acc[half * 4 + i][7];
            *(float4*)&drow[tx * 4] = o0;
            *(float4*)&drow[64 + tx * 4] = o1;
        }
    }
}

// ---------------- top-20 per row, wave-local ----------------
__global__ __launch_bounds__(256) void topk_kernel(const float* __restrict__ Dm,
                                                   int* __restrict__ idx) {
    const int w = threadIdx.x >> 6, lane = threadIdx.x & 63;
    const int p = blockIdx.x * 4 + w;
    const int b = p >> 10, pr = p & 1023;
    const float* row = Dm + ((size_t)b * NP + pr) * NP;

    unsigned long long k[16];
#pragma unroll
    for (int j = 0; j < 16; ++j) {
        int q = j * 64 + lane;
        float dv = row[q];
        unsigned u = __float_as_uint(dv);
        u = (u & 0x80000000u) ? ~u : (u | 0x80000000u);
        k[j] = ((unsigned long long)u << 32) | (unsigned)q;
    }

    for (int r = 0; r < KNN; ++r) {
        unsigned long long m = k[0];
#pragma unroll
        for (int j = 1; j < 16; ++j) m = umin64(m, k[j]);
#pragma unroll
        for (int s = 1; s < 64; s <<= 1) {
            unsigned long long o = __shfl_xor(m, s, 64);
            m = umin64(m, o);
        }
        if (lane == 0) idx[p * KNN + r] = (int)(m & 0xffffffffu);
#pragma unroll
        for (int j = 0; j < 16; ++j)
            if (k[j] == m) k[j] = ~0ull;
    }
}

// ---------------- EdgeConv as GEMM ----------------
template <int Cin, int Cout>
__global__ __launch_bounds__(256) void edge_gemm_kernel(const float* __restrict__ x,
                                                        const float* __restrict__ W,
                                                        const float* __restrict__ bias,
                                                        float* __restrict__ AB) {
    constexpr int N2 = 2 * Cout;
    constexpr int BK = (Cin < 32) ? Cin : 32;
    const int n0 = blockIdx.x * 128;
    const int p0 = blockIdx.y * 64;
    const int tid = threadIdx.x;
    const int tx = tid & 15, ty = tid >> 4;

    __shared__ float sX[BK][68];
    __shared__ float sW[BK][132];

    float acc[4][8];
#pragma unroll
    for (int i = 0; i < 4; ++i)
#pragma unroll
        for (int j = 0; j < 8; ++j) acc[i][j] = 0.f;

    for (int k0 = 0; k0 < Cin; k0 += BK) {
        if constexpr (Cin >= 32) {
#pragma unroll
            for (int u = 0; u < 2; ++u) {
                int v = tid + u * 256;
                int m = v >> 3, c4 = (v & 7) * 4;
                float4 a = *(const float4*)&x[(size_t)(p0 + m) * Cin + k0 + c4];
                sX[c4 + 0][m] = a.x;
                sX[c4 + 1][m] = a.y;
                sX[c4 + 2][m] = a.z;
                sX[c4 + 3][m] = a.w;
            }
        } else {
            for (int t = tid; t < 64 * BK; t += 256) {
                int m = t / BK, c = t - m * BK;
                sX[c][m] = x[(size_t)(p0 + m) * Cin + c];
            }
        }
        for (int t = tid; t < BK * 128; t += 256) {
            int c = t >> 7, n = t & 127;
            int nn = n0 + n;
            float w;
            if (nn < Cout)
                w = W[(size_t)(k0 + c) * Cout + nn] - W[(size_t)(Cin + k0 + c) * Cout + nn];
            else
                w = W[(size_t)(Cin + k0 + c) * Cout + (nn - Cout)];
            sW[c][n] = w;
        }
        __syncthreads();

#pragma unroll 8
        for (int c = 0; c < BK; ++c) {
            float4 a4 = *(const float4*)&sX[c][ty * 4];
            float4 w0 = *(const float4*)&sW[c][tx * 4];
            float4 w1 = *(const float4*)&sW[c][64 + tx * 4];
            float av[4] = {a4.x, a4.y, a4.z, a4.w};
#pragma unroll
            for (int i = 0; i < 4; ++i) {
                acc[i][0] += av[i] * w0.x;
                acc[i][1] += av[i] * w0.y;
                acc[i][2] += av[i] * w0.z;
                acc[i][3] += av[i] * w0.w;
                acc[i][4] += av[i] * w1.x;
                acc[i][5] += av[i] * w1.y;
                acc[i][6] += av[i] * w1.z;
                acc[i][7] += av[i] * w1.w;
            }
        }
        __syncthreads();
    }

    const bool aH0 = (n0 < Cout);
    const bool aH1 = (n0 + 64 < Cout);
    float4 z4 = {0.f, 0.f, 0.f, 0.f};
    float4 bb0 = aH0 ? *(const float4*)&bias[n0 + tx * 4] : z4;
    float4 bb1 = aH1 ? *(const float4*)&bias[n0 + 64 + tx * 4] : z4;

#pragma unroll
    for (int i = 0; i < 4; ++i) {
        float* orow = AB + (size_t)(p0 + ty * 4 + i) * N2 + n0;
        float4 o0, o1;
        o0.x = acc[i][0] + bb0.x;
        o0.y = acc[i][1] + bb0.y;
        o0.z = acc[i][2] + bb0.z;
        o0.w = acc[i][3] + bb0.w;
        o1.x = acc[i][4] + bb1.x;
        o1.y = acc[i][5] + bb1.y;
        o1.z = acc[i][6] + bb1.z;
        o1.w = acc[i][7] + bb1.w;
        *(float4*)&orow[tx * 4] = o0;
        *(float4*)&orow[64 + tx * 4] = o1;
    }
}

// ---------------- gather-max ----------------
template <int Cout>
__global__ __launch_bounds__(256) void gather_max_kernel(const float* __restrict__ AB,
                                                         const int* __restrict__ idx,
                                                         float* __restrict__ y) {
    constexpr int N2 = 2 * Cout;
    constexpr int TPP = Cout / 4;
    constexpr int PPB = 256 / TPP;
    constexpr int RS = N2 / 4;
    const int pp = threadIdx.x / TPP;
    const int t = threadIdx.x % TPP;
    const int p = blockIdx.x * PPB + pp;
    const int base = p & ~(NP - 1);

    __shared__ int s_idx[PPB][KNN];
    for (int tt = threadIdx.x; tt < PPB * KNN; tt += 256) {
        int a = tt / KNN, r = tt - a * KNN;
        s_idx[a][r] = idx[(size_t)(blockIdx.x * PPB + a) * KNN + r];
    }
    __syncthreads();

    const float4* Brow = (const float4*)(AB + (size_t)base * N2 + Cout);

    int q0 = s_idx[pp][0];
    float4 m = Brow[(size_t)q0 * RS + t];
#pragma unroll
    for (int j = 1; j < KNN; ++j) {
        int q = s_idx[pp][j];
        float4 v = Brow[(size_t)q * RS + t];
        m.x = fmaxf(m.x, v.x);
        m.y = fmaxf(m.y, v.y);
        m.z = fmaxf(m.z, v.z);
        m.w = fmaxf(m.w, v.w);
    }
    float4 a = *(const float4*)(AB + (size_t)p * N2 + 4 * t);
    float4 o;
    o.x = a.x + m.x;
    o.y = a.y + m.y;
    o.z = a.z + m.z;
    o.w = a.w + m.w;
    *(float4*)(y + (size_t)p * Cout + 4 * t) = o;
}

// ---------------- fused cat-GEMM + max/mean pool ----------------
// 128x128 tile, 8x8/thread, double-buffered LDS (1 barrier/chunk), XCD swizzle.
// Writes per-(p-block, col) partials (pre-bias); bias deferred to fc_a.
__global__ __launch_bounds__(256, 2) void gemm_cat_pool_kernel(
        const float* __restrict__ x1, const float* __restrict__ x2,
        const float* __restrict__ x3, const float* __restrict__ x4,
        const float* __restrict__ Wm,
        float* __restrict__ pmax, float* __restrict__ psum) {
    const int bid = blockIdx.x;                  // 512 blocks
    const int xcd = bid & 7, pos = bid >> 3;
    const int nb = pos & 7, pb = (xcd << 3) | (pos >> 3);
    const int n0 = nb * 128, p0 = pb * 128;
    const int tid = threadIdx.x;
    const int tx = tid & 15, ty = tid >> 4;

    __shared__ float sA[2][32][128];
    __shared__ float sW[2][32][132];

    float acc[8][8];
#pragma unroll
    for (int i = 0; i < 8; ++i)
#pragma unroll
        for (int j = 0; j < 8; ++j) acc[i][j] = 0.f;

    const int am = tid >> 3;          // A: row within 32-row group
    const int ac4 = (tid & 7) * 4;    // A: k-offset
    const int wc = tid >> 5;          // W: k within 8-row group
    const int wn4 = (tid & 31) * 4;   // W: col offset

    float4 ra0, ra1, ra2, ra3, rw0, rw1, rw2, rw3;

#define GC_LOAD(ck)                                                                      \
    {                                                                                    \
        int k0 = (ck) * 32;                                                              \
        const float* src;                                                                \
        int cin, coff;                                                                   \
        if (k0 < 64) { src = x1; cin = 64; coff = k0; }                                  \
        else if (k0 < 128) { src = x2; cin = 64; coff = k0 - 64; }                       \
        else if (k0 < 256) { src = x3; cin = 128; coff = k0 - 128; }                     \
        else { src = x4; cin = 256; coff = k0 - 256; }                                   \
        ra0 = *(const float4*)&src[(size_t)(p0 + am) * cin + coff + ac4];                \
        ra1 = *(const float4*)&src[(size_t)(p0 + am + 32) * cin + coff + ac4];           \
        ra2 = *(const float4*)&src[(size_t)(p0 + am + 64) * cin + coff + ac4];           \
        ra3 = *(const float4*)&src[(size_t)(p0 + am + 96) * cin + coff + ac4];           \
        rw0 = *(const float4*)&Wm[(size_t)(k0 + wc) * 1024 + n0 + wn4];                  \
        rw1 = *(const float4*)&Wm[(size_t)(k0 + wc + 8) * 1024 + n0 + wn4];              \
        rw2 = *(const float4*)&Wm[(size_t)(k0 + wc + 16) * 1024 + n0 + wn4];             \
        rw3 = *(const float4*)&Wm[(size_t)(k0 + wc + 24) * 1024 + n0 + wn4];             \
    }

#define GC_WRITE(buf)                                                                    \
    {                                                                                    \
        sA[buf][ac4 + 0][swz(ac4 + 0, am)] = ra0.x;                                      \
        sA[buf][ac4 + 1][swz(ac4 + 1, am)] = ra0.y;                                      \
        sA[buf][ac4 + 2][swz(ac4 + 2, am)] = ra0.z;                                      \
        sA[buf][ac4 + 3][swz(ac4 + 3, am)] = ra0.w;                                      \
        sA[buf][ac4 + 0][swz(ac4 + 0, am + 32)] = ra1.x;                                 \
        sA[buf][ac4 + 1][swz(ac4 + 1, am + 32)] = ra1.y;                                 \
        sA[buf][ac4 + 2][swz(ac4 + 2, am + 32)] = ra1.z;                                 \
        sA[buf][ac4 + 3][swz(ac4 + 3, am + 32)] = ra1.w;                                 \
        sA[buf][ac4 + 0][swz(ac4 + 0, am + 64)] = ra2.x;                                 \
        sA[buf][ac4 + 1][swz(ac4 + 1, am + 64)] = ra2.y;                                 \
        sA[buf][ac4 + 2][swz(ac4 + 2, am + 64)] = ra2.z;                                 \
        sA[buf][ac4 + 3][swz(ac4 + 3, am + 64)] = ra2.w;                                 \
        sA[buf][ac4 + 0][swz(ac4 + 0, am + 96)] = ra3.x;                                 \
        sA[buf][ac4 + 1][swz(ac4 + 1, am + 96)] = ra3.y;                                 \
        sA[buf][ac4 + 2][swz(ac4 + 2, am + 96)] = ra3.z;                                 \
        sA[buf][ac4 + 3][swz(ac4 + 3, am + 96)] = ra3.w;                                 \
        *(float4*)&sW[buf][wc][wn4] = rw0;                                               \
        *(float4*)&sW[buf][wc + 8][wn4] = rw1;                                           \
        *(float4*)&sW[buf][wc + 16][wn4] = rw2;                                          \
        *(float4*)&sW[buf][wc + 24][wn4] = rw3;                                          \
    }

    GC_LOAD(0);
    GC_WRITE(0);
    __syncthreads();

    for (int ck = 0; ck < 16; ++ck) {
        const int buf = ck & 1;
        if (ck < 15) GC_LOAD(ck + 1);

#pragma unroll 4
        for (int c = 0; c < 32; ++c) {
            int xc = (c >> 2) & 7;
            int ga = ty ^ xc;
            float4 a0 = *(const float4*)&sA[buf][c][ga * 4];
            float4 a1 = *(const float4*)&sA[buf][c][(16 + ga) * 4];
            float4 w0 = *(const float4*)&sW[buf][c][tx * 4];
            float4 w1 = *(const float4*)&sW[buf][c][64 + tx * 4];
            float av[8] = {a0.x, a0.y, a0.z, a0.w, a1.x, a1.y, a1.z, a1.w};
            float wv[8] = {w0.x, w0.y, w0.z, w0.w, w1.x, w1.y, w1.z, w1.w};
#pragma unroll
            for (int i = 0; i < 8; ++i)
#pragma unroll
                for (int j = 0; j < 8; ++j) acc[i][j] += av[i] * wv[j];
        }
        if (ck < 15) GC_WRITE(buf ^ 1);
        __syncthreads();
    }

    // ---- per-thread col partials over its 8 rows ----
    float pjm[8], pjs[8];
#pragma unroll
    for (int j = 0; j < 8; ++j) {
        float m = acc[0][j], s = acc[0][j];
#pragma unroll
        for (int i = 1; i < 8; ++i) {
            m = fmaxf(m, acc[i][j]);
            s += acc[i][j];
        }
        pjm[j] = m;
        pjs[j] = s;
    }
    // reuse sA as scratch (all reads drained by the final barrier above)
    float* smax = (float*)sA;          // 2048 floats
    float* ssum = (float*)sA + 2048;   // 2048 floats
#pragma unroll
    for (int j = 0; j < 8; ++j) {
        smax[tid * 8 + j] = pjm[j];
        ssum[tid * 8 + j] = pjs[j];
    }
    __syncthreads();

    // 256 jobs: 128 cols x {max,sum}
    {
        int c = tid & 127, stat = tid >> 7;
        int txx = (c & 63) >> 2;
        int jj = (c & 3) + ((c >= 64) ? 4 : 0);
        if (stat == 0) {
            float m = smax[(txx)*8 + jj];
            for (int tyy = 1; tyy < 16; ++tyy) m = fmaxf(m, smax[(tyy * 16 + txx) * 8 + jj]);
            pmax[(size_t)pb * 1024 + n0 + c] = m;
        } else {
            float s = ssum[(txx)*8 + jj];
            for (int tyy = 1; tyy < 16; ++tyy) s += ssum[(tyy * 16 + txx) * 8 + jj];
            psum[(size_t)pb * 1024 + n0 + c] = s;
        }
    }
#undef GC_LOAD
#undef GC_WRITE
}

// ---------------- fc_a: combines pool partials (+deferred bm), [8,2048]x[2048,512] ----
__global__ __launch_bounds__(256) void fc_a_kernel(const float* __restrict__ pmax,
                                                   const float* __restrict__ psum,
                                                   const float* __restrict__ bm,
                                                   const float* __restrict__ Wa,
                                                   const float* __restrict__ ba,
                                                   float* __restrict__ ha) {
    const int b = blockIdx.y;
    const int n0 = blockIdx.x * 64;
    const int tid = threadIdx.x;
    __shared__ float gm[2048];
    __shared__ float4 part[16][16];

    for (int c = tid; c < 1024; c += 256) {
        float m = pmax[(size_t)(b * 8) * 1024 + c];
        float s = psum[(size_t)(b * 8) * 1024 + c];
#pragma unroll
        for (int z = 1; z < 8; ++z) {
            m = fmaxf(m, pmax[(size_t)(b * 8 + z) * 1024 + c]);
            s += psum[(size_t)(b * 8 + z) * 1024 + c];
        }
        gm[c] = m + bm[c];
        gm[1024 + c] = s * (1.0f / 1024.0f) + bm[c];
    }
    __syncthreads();

    const int cg = tid & 15, kp = tid >> 4;
    const int co = n0 + cg * 4;
    float4 acc = {0.f, 0.f, 0.f, 0.f};
    const float* Wp = Wa + (size_t)(kp * 128) * 512 + co;
    const float* gp = gm + kp * 128;
#pragma unroll 8
    for (int k = 0; k < 128; ++k) {
        float g = gp[k];
        float4 w = *(const float4*)&Wp[(size_t)k * 512];
        acc.x += g * w.x;
        acc.y += g * w.y;
        acc.z += g * w.z;
        acc.w += g * w.w;
    }
    part[kp][cg] = acc;
    __syncthreads();
    if (tid < 16) {
        float4 s = part[0][tid];
#pragma unroll
        for (int z = 1; z < 16; ++z) {
            float4 p = part[z][tid];
            s.x += p.x; s.y += p.y; s.z += p.z; s.w += p.w;
        }
        float4 bb = *(const float4*)&ba[n0 + tid * 4];
        s.x += bb.x; s.y += bb.y; s.z += bb.z; s.w += bb.w;
        *(float4*)&ha[(size_t)b * 512 + n0 + tid * 4] = s;
    }
}

__global__ __launch_bounds__(256) void bn_leaky_kernel(float* __restrict__ h,
                                                       const float* __restrict__ g,
                                                       const float* __restrict__ be,
                                                       int ncol) {
    int co = blockIdx.x * 256 + threadIdx.x;
    if (co >= ncol) return;
    float mu = 0.f;
    for (int b = 0; b < NB; ++b) mu += h[b * ncol + co];
    mu *= 0.125f;
    float var = 0.f;
    for (int b = 0; b < NB; ++b) {
        float d = h[b * ncol + co] - mu;
        var += d * d;
    }
    var *= 0.125f;
    float inv = 1.0f / sqrtf(var + 1e-5f);
    for (int b = 0; b < NB; ++b) {
        float v = (h[b * ncol + co] - mu) * inv * g[co] + be[co];
        h[b * ncol + co] = v >= 0.f ? v : 0.2f * v;
    }
}

// ---------------- fc_b: [8,512]x[512,256], K-split 16 ----------------
__global__ __launch_bounds__(256) void fc_b_kernel(const float* __restrict__ ha,
                                                   const float* __restrict__ Wb,
                                                   const float* __restrict__ bb,
                                                   float* __restrict__ hb) {
    const int b = blockIdx.y;
    const int n0 = blockIdx.x * 64;
    const int tid = threadIdx.x;
    __shared__ float sh[512];
    __shared__ float4 part[16][16];

    for (int c = tid; c < 512; c += 256) sh[c] = ha[(size_t)b * 512 + c];
    __syncthreads();

    const int cg = tid & 15, kp = tid >> 4;
    const int co = n0 + cg * 4;
    float4 acc = {0.f, 0.f, 0.f, 0.f};
#pragma unroll 8
    for (int k = 0; k < 32; ++k) {
        float g = sh[kp * 32 + k];
        float4 w = *(const float4*)&Wb[(size_t)(kp * 32 + k) * 256 + co];
        acc.x += g * w.x;
        acc.y += g * w.y;
        acc.z += g * w.z;
        acc.w += g * w.w;
    }
    part[kp][cg] = acc;
    __syncthreads();
    if (tid < 16) {
        float4 s = part[0][tid];
#pragma unroll
        for (int z = 1; z < 16; ++z) {
            float4 p = part[z][tid];
            s.x += p.x; s.y += p.y; s.z += p.z; s.w += p.w;
        }
        float4 bv = *(const float4*)&bb[n0 + tid * 4];
        s.x += bv.x; s.y += bv.y; s.z += bv.z; s.w += bv.w;
        *(float4*)&hb[(size_t)b * 256 + n0 + tid * 4] = s;
    }
}

__global__ __launch_bounds__(256) void fc_c_kernel(const float* __restrict__ hb,
                                                   const float* __restrict__ Wc,
                                                   const float* __restrict__ bc,
                                                   float* __restrict__ outp) {
    int t = blockIdx.x * 256 + threadIdx.x;  // 8*40
    if (t >= 8 * 40) return;
    int b = t / 40, o = t - b * 40;
    float s = bc[o];
    for (int c = 0; c < 256; ++c) s += hb[b * 256 + c] * Wc[c * 40 + o];
    outp[t] = s;
}

extern "C" void kernel_launch(void* const* d_in, const int* in_sizes, int n_in,
                              void* d_out, int out_size, void* d_ws, size_t ws_size,
                              hipStream_t stream) {
    const float* pos = (const float*)d_in[0];
    const float* W1 = (const float*)d_in[2];
    const float* b1 = (const float*)d_in[3];
    const float* W2 = (const float*)d_in[4];
    const float* b2 = (const float*)d_in[5];
    const float* W3 = (const float*)d_in[6];
    const float* b3 = (const float*)d_in[7];
    const float* W4 = (const float*)d_in[8];
    const float* b4 = (const float*)d_in[9];
    const float* Wm = (const float*)d_in[10];
    const float* bm = (const float*)d_in[11];
    const float* Wa = (const float*)d_in[12];
    const float* ba = (const float*)d_in[13];
    const float* ga = (const float*)d_in[14];
    const float* bea = (const float*)d_in[15];
    const float* Wb = (const float*)d_in[16];
    const float* bb = (const float*)d_in[17];
    const float* gb = (const float*)d_in[18];
    const float* beb = (const float*)d_in[19];
    const float* Wc = (const float*)d_in[20];
    const float* bc = (const float*)d_in[21];
    float* out = (float*)d_out;

    char* ws = (char*)d_ws;
    size_t off = 0;
    auto alloc = [&](size_t bytes) {
        void* p = ws + off;
        off += (bytes + 255) & ~(size_t)255;
        return p;
    };
    int* idx = (int*)alloc((size_t)NPTS * KNN * 4);
    float* x1 = (float*)alloc((size_t)NPTS * 64 * 4);
    float* x2 = (float*)alloc((size_t)NPTS * 64 * 4);
    float* x3 = (float*)alloc((size_t)NPTS * 128 * 4);
    float* x4 = (float*)alloc((size_t)NPTS * 256 * 4);
    float* scratch = (float*)alloc((size_t)NPTS * 1024 * 4);  // Dm / AB
    float* pmax = (float*)alloc((size_t)64 * 1024 * 4);
    float* psum = (float*)alloc((size_t)64 * 1024 * 4);
    float* ha = (float*)alloc(NB * 512 * 4);
    float* hb = (float*)alloc(NB * 256 * 4);
    (void)ws_size;

    float* Dm = scratch;
    float* AB = scratch;

    dim3 dgrid128(8, 8, 8);

    // layer 1 (C=3 -> 64)
    dist3_kernel<<<dim3(16, 16, 8), 256, 0, stream>>>(pos, Dm);
    topk_kernel<<<NPTS / 4, 256, 0, stream>>>(Dm, idx);
    edge_gemm_kernel<3, 64><<<dim3(1, 128), 256, 0, stream>>>(pos, W1, b1, AB);
    gather_max_kernel<64><<<NPTS / 16, 256, 0, stream>>>(AB, idx, x1);

    // layer 2 (64 -> 64)
    dist128_kernel<64><<<dgrid128, 256, 0, stream>>>(x1, Dm);
    topk_kernel<<<NPTS / 4, 256, 0, stream>>>(Dm, idx);
    edge_gemm_kernel<64, 64><<<dim3(1, 128), 256, 0, stream>>>(x1, W2, b2, AB);
    gather_max_kernel<64><<<NPTS / 16, 256, 0, stream>>>(AB, idx, x2);

    // layer 3 (64 -> 128)
    dist128_kernel<64><<<dgrid128, 256, 0, stream>>>(x2, Dm);
    topk_kernel<<<NPTS / 4, 256, 0, stream>>>(Dm, idx);
    edge_gemm_kernel<64, 128><<<dim3(2, 128), 256, 0, stream>>>(x2, W3, b3, AB);
    gather_max_kernel<128><<<NPTS / 8, 256, 0, stream>>>(AB, idx, x3);

    // layer 4 (128 -> 256)
    dist128_kernel<128><<<dgrid128, 256, 0, stream>>>(x3, Dm);
    topk_kernel<<<NPTS / 4, 256, 0, stream>>>(Dm, idx);
    edge_gemm_kernel<128, 256><<<dim3(4, 128), 256, 0, stream>>>(x3, W4, b4, AB);
    gather_max_kernel<256><<<NPTS / 4, 256, 0, stream>>>(AB, idx, x4);

    // fused cat@Wm + max/mean pool (bias deferred to fc_a)
    gemm_cat_pool_kernel<<<512, 256, 0, stream>>>(x1, x2, x3, x4, Wm, pmax, psum);

    // head
    fc_a_kernel<<<dim3(8, NB), 256, 0, stream>>>(pmax, psum, bm, Wa, ba, ha);
    bn_leaky_kernel<<<2, 256, 0, stream>>>(ha, ga, bea, 512);
    fc_b_kernel<<<dim3(4, NB), 256, 0, stream>>>(ha, Wb, bb, hb);
    bn_leaky_kernel<<<1, 256, 0, stream>>>(hb, gb, beb, 256);
    fc_c_kernel<<<2, 256, 0, stream>>>(hb, Wc, bc, out);
}

// Round 7
// 440.997 us; speedup vs baseline: 5.1828x; 1.0758x over previous
//
#include <hip/hip_runtime.h>
#include <hip/hip_bf16.h>

#define NB 8
#define NP 1024
#define NPTS (NB * NP)
#define KNN 20

using bf16x8 = __attribute__((ext_vector_type(8))) short;
using f32x4 = __attribute__((ext_vector_type(4))) float;

static __device__ __forceinline__ unsigned long long umin64(unsigned long long a,
                                                            unsigned long long b) {
    return a < b ? a : b;
}

// XOR swizzle for K-major transposed LDS tiles (stride 128 floats, no pad).
static __device__ __forceinline__ int swz(int k, int m) {
    return ((((m >> 2) ^ ((k >> 2) & 7)) << 2) | (m & 3));
}

static __device__ __forceinline__ void split_bf16(float v, unsigned short& h,
                                                  unsigned short& l) {
    __hip_bfloat16 hb = __float2bfloat16(v);
    float hf = __bfloat162float(hb);
    __hip_bfloat16 lb = __float2bfloat16(v - hf);
    h = *(unsigned short*)&hb;
    l = *(unsigned short*)&lb;
}

// ---------------- dist for C=3 (layer 1) ----------------
__global__ __launch_bounds__(256) void dist3_kernel(const float* __restrict__ x,
                                                    float* __restrict__ Dm) {
    constexpr int C = 3;
    const int b = blockIdx.z;
    const int p0 = blockIdx.y * 64;
    const int q0 = blockIdx.x * 64;
    const int tid = threadIdx.x;
    const int tx = tid & 15, ty = tid >> 4;
    const float* xb = x + (size_t)b * NP * C;

    __shared__ float sA[C][68];
    __shared__ float sB[C][68];
    __shared__ float sqa[64];
    __shared__ float sqb[64];

    for (int t = tid; t < 64 * C; t += 256) {
        int m = t / C, c = t - m * C;
        sA[c][m] = xb[(size_t)(p0 + m) * C + c];
        sB[c][m] = xb[(size_t)(q0 + m) * C + c];
    }
    __syncthreads();

    if (tid < 64) {
        float s = 0.f;
#pragma unroll
        for (int c = 0; c < C; ++c) s += sA[c][tid] * sA[c][tid];
        sqa[tid] = s;
    } else if (tid < 128) {
        float s = 0.f;
#pragma unroll
        for (int c = 0; c < C; ++c) s += sB[c][tid - 64] * sB[c][tid - 64];
        sqb[tid - 64] = s;
    }

    float acc[4][4];
#pragma unroll
    for (int i = 0; i < 4; ++i)
#pragma unroll
        for (int j = 0; j < 4; ++j) acc[i][j] = 0.f;

#pragma unroll
    for (int c = 0; c < C; ++c) {
        float a4[4], b4[4];
#pragma unroll
        for (int i = 0; i < 4; ++i) a4[i] = sA[c][ty * 4 + i];
#pragma unroll
        for (int j = 0; j < 4; ++j) b4[j] = sB[c][tx * 4 + j];
#pragma unroll
        for (int i = 0; i < 4; ++i)
#pragma unroll
            for (int j = 0; j < 4; ++j) acc[i][j] += a4[i] * b4[j];
    }
    __syncthreads();

#pragma unroll
    for (int i = 0; i < 4; ++i) {
        int p = p0 + ty * 4 + i;
        float sqp = sqa[ty * 4 + i];
        float* drow = Dm + ((size_t)b * NP + p) * NP + q0;
#pragma unroll
        for (int j = 0; j < 4; ++j) {
            int q = tx * 4 + j;
            drow[q] = sqp + sqb[q] - 2.0f * acc[i][j];
        }
    }
}

// ---------------- dist for C>=32: 128x128 quadrant tile, 8x8/thread ----------------
template <int C>
__global__ __launch_bounds__(256, 2) void dist128_kernel(const float* __restrict__ x,
                                                         float* __restrict__ Dm) {
    const int b = blockIdx.z;
    const int p0 = blockIdx.y * 128;
    const int q0 = blockIdx.x * 128;
    const int tid = threadIdx.x;
    const int tx = tid & 15, ty = tid >> 4;
    const float* xb = x + (size_t)b * NP * C;

    __shared__ float sA[32][128];
    __shared__ float sB[32][128];
    __shared__ float sqa[128];
    __shared__ float sqb[128];

    float acc[8][8];
#pragma unroll
    for (int i = 0; i < 8; ++i)
#pragma unroll
        for (int j = 0; j < 8; ++j) acc[i][j] = 0.f;
    float sqreg = 0.f;

    for (int k0 = 0; k0 < C; k0 += 32) {
#pragma unroll
        for (int u = 0; u < 4; ++u) {
            int v = tid + u * 256;
            int m = v >> 3, c4 = (v & 7) * 4;
            float4 a = *(const float4*)&xb[(size_t)(p0 + m) * C + k0 + c4];
            sA[c4 + 0][swz(c4 + 0, m)] = a.x;
            sA[c4 + 1][swz(c4 + 1, m)] = a.y;
            sA[c4 + 2][swz(c4 + 2, m)] = a.z;
            sA[c4 + 3][swz(c4 + 3, m)] = a.w;
            float4 bb = *(const float4*)&xb[(size_t)(q0 + m) * C + k0 + c4];
            sB[c4 + 0][swz(c4 + 0, m)] = bb.x;
            sB[c4 + 1][swz(c4 + 1, m)] = bb.y;
            sB[c4 + 2][swz(c4 + 2, m)] = bb.z;
            sB[c4 + 3][swz(c4 + 3, m)] = bb.w;
        }
        __syncthreads();

        if (tid < 128) {
#pragma unroll 8
            for (int c = 0; c < 32; ++c) {
                float v = sA[c][swz(c, tid)];
                sqreg += v * v;
            }
        } else {
#pragma unroll 8
            for (int c = 0; c < 32; ++c) {
                float v = sB[c][swz(c, tid - 128)];
                sqreg += v * v;
            }
        }

#pragma unroll 4
        for (int c = 0; c < 32; ++c) {
            int xc = (c >> 2) & 7;
            int ga = ty ^ xc, gb = tx ^ xc;
            float4 a0 = *(const float4*)&sA[c][ga * 4];
            float4 a1 = *(const float4*)&sA[c][(16 + ga) * 4];
            float4 b0 = *(const float4*)&sB[c][gb * 4];
            float4 b1 = *(const float4*)&sB[c][(16 + gb) * 4];
            float av[8] = {a0.x, a0.y, a0.z, a0.w, a1.x, a1.y, a1.z, a1.w};
            float bv[8] = {b0.x, b0.y, b0.z, b0.w, b1.x, b1.y, b1.z, b1.w};
#pragma unroll
            for (int i = 0; i < 8; ++i)
#pragma unroll
                for (int j = 0; j < 8; ++j) acc[i][j] += av[i] * bv[j];
        }
        __syncthreads();
    }

    if (tid < 128) sqa[tid] = sqreg;
    else sqb[tid - 128] = sqreg;
    __syncthreads();

#pragma unroll
    for (int half = 0; half < 2; ++half) {
#pragma unroll
        for (int i = 0; i < 4; ++i) {
            int r = half * 64 + ty * 4 + i;
            float sp = sqa[r];
            float* drow = Dm + ((size_t)b * NP + p0 + r) * NP + q0;
            float4 o0, o1;
            o0.x = sp + sqb[tx * 4 + 0] - 2.0f * acc[half * 4 + i][0];
            o0.y = sp + sqb[tx * 4 + 1] - 2.0f * acc[half * 4 + i][1];
            o0.z = sp + sqb[tx * 4 + 2] - 2.0f * acc[half * 4 + i][2];
            o0.w = sp + sqb[tx * 4 + 3] - 2.0f * acc[half * 4 + i][3];
            o1.x = sp + sqb[64 + tx * 4 + 0] - 2.0f * acc[half * 4 + i][4];
            o1.y = sp + sqb[64 + tx * 4 + 1] - 2.0f * acc[half * 4 + i][5];
            o1.z = sp + sqb[64 + tx * 4 + 2] - 2.0f * acc[half * 4 + i][6];
            o1.w = sp + sqb[64 + tx * 4 + 3] - 2.0f * acc[half * 4 + i][7];
            *(float4*)&drow[tx * 4] = o0;
            *(float4*)&drow[64 + tx * 4] = o1;
        }
    }
}

// ---------------- top-20 per row, wave-local ----------------
__global__ __launch_bounds__(256) void topk_kernel(const float* __restrict__ Dm,
                                                   int* __restrict__ idx) {
    const int w = threadIdx.x >> 6, lane = threadIdx.x & 63;
    const int p = blockIdx.x * 4 + w;
    const int b = p >> 10, pr = p & 1023;
    const float* row = Dm + ((size_t)b * NP + pr) * NP;

    unsigned long long k[16];
#pragma unroll
    for (int j = 0; j < 16; ++j) {
        int q = j * 64 + lane;
        float dv = row[q];
        unsigned u = __float_as_uint(dv);
        u = (u & 0x80000000u) ? ~u : (u | 0x80000000u);
        k[j] = ((unsigned long long)u << 32) | (unsigned)q;
    }

    for (int r = 0; r < KNN; ++r) {
        unsigned long long m = k[0];
#pragma unroll
        for (int j = 1; j < 16; ++j) m = umin64(m, k[j]);
#pragma unroll
        for (int s = 1; s < 64; s <<= 1) {
            unsigned long long o = __shfl_xor(m, s, 64);
            m = umin64(m, o);
        }
        if (lane == 0) idx[p * KNN + r] = (int)(m & 0xffffffffu);
#pragma unroll
        for (int j = 0; j < 16; ++j)
            if (k[j] == m) k[j] = ~0ull;
    }
}

// ---------------- EdgeConv as GEMM ----------------
template <int Cin, int Cout>
__global__ __launch_bounds__(256) void edge_gemm_kernel(const float* __restrict__ x,
                                                        const float* __restrict__ W,
                                                        const float* __restrict__ bias,
                                                        float* __restrict__ AB) {
    constexpr int N2 = 2 * Cout;
    constexpr int BK = (Cin < 32) ? Cin : 32;
    const int n0 = blockIdx.x * 128;
    const int p0 = blockIdx.y * 64;
    const int tid = threadIdx.x;
    const int tx = tid & 15, ty = tid >> 4;

    __shared__ float sX[BK][68];
    __shared__ float sW[BK][132];

    float acc[4][8];
#pragma unroll
    for (int i = 0; i < 4; ++i)
#pragma unroll
        for (int j = 0; j < 8; ++j) acc[i][j] = 0.f;

    for (int k0 = 0; k0 < Cin; k0 += BK) {
        if constexpr (Cin >= 32) {
#pragma unroll
            for (int u = 0; u < 2; ++u) {
                int v = tid + u * 256;
                int m = v >> 3, c4 = (v & 7) * 4;
                float4 a = *(const float4*)&x[(size_t)(p0 + m) * Cin + k0 + c4];
                sX[c4 + 0][m] = a.x;
                sX[c4 + 1][m] = a.y;
                sX[c4 + 2][m] = a.z;
                sX[c4 + 3][m] = a.w;
            }
        } else {
            for (int t = tid; t < 64 * BK; t += 256) {
                int m = t / BK, c = t - m * BK;
                sX[c][m] = x[(size_t)(p0 + m) * Cin + c];
            }
        }
        for (int t = tid; t < BK * 128; t += 256) {
            int c = t >> 7, n = t & 127;
            int nn = n0 + n;
            float w;
            if (nn < Cout)
                w = W[(size_t)(k0 + c) * Cout + nn] - W[(size_t)(Cin + k0 + c) * Cout + nn];
            else
                w = W[(size_t)(Cin + k0 + c) * Cout + (nn - Cout)];
            sW[c][n] = w;
        }
        __syncthreads();

#pragma unroll 8
        for (int c = 0; c < BK; ++c) {
            float4 a4 = *(const float4*)&sX[c][ty * 4];
            float4 w0 = *(const float4*)&sW[c][tx * 4];
            float4 w1 = *(const float4*)&sW[c][64 + tx * 4];
            float av[4] = {a4.x, a4.y, a4.z, a4.w};
#pragma unroll
            for (int i = 0; i < 4; ++i) {
                acc[i][0] += av[i] * w0.x;
                acc[i][1] += av[i] * w0.y;
                acc[i][2] += av[i] * w0.z;
                acc[i][3] += av[i] * w0.w;
                acc[i][4] += av[i] * w1.x;
                acc[i][5] += av[i] * w1.y;
                acc[i][6] += av[i] * w1.z;
                acc[i][7] += av[i] * w1.w;
            }
        }
        __syncthreads();
    }

    const bool aH0 = (n0 < Cout);
    const bool aH1 = (n0 + 64 < Cout);
    float4 z4 = {0.f, 0.f, 0.f, 0.f};
    float4 bb0 = aH0 ? *(const float4*)&bias[n0 + tx * 4] : z4;
    float4 bb1 = aH1 ? *(const float4*)&bias[n0 + 64 + tx * 4] : z4;

#pragma unroll
    for (int i = 0; i < 4; ++i) {
        float* orow = AB + (size_t)(p0 + ty * 4 + i) * N2 + n0;
        float4 o0, o1;
        o0.x = acc[i][0] + bb0.x;
        o0.y = acc[i][1] + bb0.y;
        o0.z = acc[i][2] + bb0.z;
        o0.w = acc[i][3] + bb0.w;
        o1.x = acc[i][4] + bb1.x;
        o1.y = acc[i][5] + bb1.y;
        o1.z = acc[i][6] + bb1.z;
        o1.w = acc[i][7] + bb1.w;
        *(float4*)&orow[tx * 4] = o0;
        *(float4*)&orow[64 + tx * 4] = o1;
    }
}

// ---------------- gather-max ----------------
template <int Cout>
__global__ __launch_bounds__(256) void gather_max_kernel(const float* __restrict__ AB,
                                                         const int* __restrict__ idx,
                                                         float* __restrict__ y) {
    constexpr int N2 = 2 * Cout;
    constexpr int TPP = Cout / 4;
    constexpr int PPB = 256 / TPP;
    constexpr int RS = N2 / 4;
    const int pp = threadIdx.x / TPP;
    const int t = threadIdx.x % TPP;
    const int p = blockIdx.x * PPB + pp;
    const int base = p & ~(NP - 1);

    __shared__ int s_idx[PPB][KNN];
    for (int tt = threadIdx.x; tt < PPB * KNN; tt += 256) {
        int a = tt / KNN, r = tt - a * KNN;
        s_idx[a][r] = idx[(size_t)(blockIdx.x * PPB + a) * KNN + r];
    }
    __syncthreads();

    const float4* Brow = (const float4*)(AB + (size_t)base * N2 + Cout);

    int q0 = s_idx[pp][0];
    float4 m = Brow[(size_t)q0 * RS + t];
#pragma unroll
    for (int j = 1; j < KNN; ++j) {
        int q = s_idx[pp][j];
        float4 v = Brow[(size_t)q * RS + t];
        m.x = fmaxf(m.x, v.x);
        m.y = fmaxf(m.y, v.y);
        m.z = fmaxf(m.z, v.z);
        m.w = fmaxf(m.w, v.w);
    }
    float4 a = *(const float4*)(AB + (size_t)p * N2 + 4 * t);
    float4 o;
    o.x = a.x + m.x;
    o.y = a.y + m.y;
    o.z = a.z + m.z;
    o.w = a.w + m.w;
    *(float4*)(y + (size_t)p * Cout + 4 * t) = o;
}

// ---------------- convert cat(x1..x4) to bf16 hi/lo k-panels [64][8192][8] ----------
__global__ __launch_bounds__(256) void convert_cat_kernel(
        const float* __restrict__ x1, const float* __restrict__ x2,
        const float* __restrict__ x3, const float* __restrict__ x4,
        unsigned short* __restrict__ Ah, unsigned short* __restrict__ Al) {
    int g = blockIdx.x * 256 + threadIdx.x;  // 524288 jobs
    int p = g & 8191, ks = g >> 13;
    const float* src;
    if (ks < 8) src = x1 + (size_t)p * 64 + ks * 8;
    else if (ks < 16) src = x2 + (size_t)p * 64 + (ks - 8) * 8;
    else if (ks < 32) src = x3 + (size_t)p * 128 + (ks - 16) * 8;
    else src = x4 + (size_t)p * 256 + (ks - 32) * 8;
    float4 v0 = ((const float4*)src)[0];
    float4 v1 = ((const float4*)src)[1];
    float v[8] = {v0.x, v0.y, v0.z, v0.w, v1.x, v1.y, v1.z, v1.w};
    unsigned short h[8], l[8];
#pragma unroll
    for (int j = 0; j < 8; ++j) split_bf16(v[j], h[j], l[j]);
    size_t ci = (size_t)ks * 8192 + p;
    uint4 hp, lp;
    hp.x = h[0] | ((unsigned)h[1] << 16);
    hp.y = h[2] | ((unsigned)h[3] << 16);
    hp.z = h[4] | ((unsigned)h[5] << 16);
    hp.w = h[6] | ((unsigned)h[7] << 16);
    lp.x = l[0] | ((unsigned)l[1] << 16);
    lp.y = l[2] | ((unsigned)l[3] << 16);
    lp.z = l[4] | ((unsigned)l[5] << 16);
    lp.w = l[6] | ((unsigned)l[7] << 16);
    ((uint4*)Ah)[ci] = hp;
    ((uint4*)Al)[ci] = lp;
}

// ---------------- convert+transpose Wm to bf16 hi/lo k-panels [64][1024][8] --------
__global__ __launch_bounds__(256) void convert_w_kernel(const float* __restrict__ Wm,
                                                        unsigned short* __restrict__ Wh,
                                                        unsigned short* __restrict__ Wl) {
    int g = blockIdx.x * 256 + threadIdx.x;  // 65536 jobs
    int n = g & 1023, ks = g >> 10;
    unsigned short h[8], l[8];
#pragma unroll
    for (int j = 0; j < 8; ++j) {
        float v = Wm[(size_t)(ks * 8 + j) * 1024 + n];
        split_bf16(v, h[j], l[j]);
    }
    size_t ci = (size_t)ks * 1024 + n;
    uint4 hp, lp;
    hp.x = h[0] | ((unsigned)h[1] << 16);
    hp.y = h[2] | ((unsigned)h[3] << 16);
    hp.z = h[4] | ((unsigned)h[5] << 16);
    hp.w = h[6] | ((unsigned)h[7] << 16);
    lp.x = l[0] | ((unsigned)l[1] << 16);
    lp.y = l[2] | ((unsigned)l[3] << 16);
    lp.z = l[4] | ((unsigned)l[5] << 16);
    lp.w = l[6] | ((unsigned)l[7] << 16);
    ((uint4*)Wh)[ci] = hp;
    ((uint4*)Wl)[ci] = lp;
}

// ---------------- catmean[b][512] = mean over p of cat ----------------
__global__ __launch_bounds__(256) void catmean_kernel(
        const float* __restrict__ x1, const float* __restrict__ x2,
        const float* __restrict__ x3, const float* __restrict__ x4,
        float* __restrict__ catmean) {
    const int n0 = blockIdx.x * 128;
    const int b = blockIdx.y;
    const int tid = threadIdx.x;
    const int col = n0 + (tid & 127);
    const int half = tid >> 7;
    __shared__ float sred[256];

    const float* src;
    int cw, coff;
    if (col < 64) { src = x1; cw = 64; coff = col; }
    else if (col < 128) { src = x2; cw = 64; coff = col - 64; }
    else if (col < 256) { src = x3; cw = 128; coff = col - 128; }
    else { src = x4; cw = 256; coff = col - 256; }

    float s = 0.f;
    const float* base = src + ((size_t)b * NP + half * 512) * cw + coff;
    for (int p = 0; p < 512; ++p) s += base[(size_t)p * cw];
    sred[tid] = s;
    __syncthreads();
    if (tid < 128)
        catmean[(size_t)b * 512 + col] = (sred[tid] + sred[tid + 128]) * (1.0f / 1024.0f);
}

// ---------------- gmeanv[b][1024] = catmean . Wm + bm ----------------
__global__ __launch_bounds__(256) void gmean_kernel(const float* __restrict__ catmean,
                                                    const float* __restrict__ Wm,
                                                    const float* __restrict__ bm,
                                                    float* __restrict__ gmeanv) {
    const int n0 = blockIdx.x * 128;
    const int b = blockIdx.y;
    const int tid = threadIdx.x;
    const int cg = tid & 31, kp = tid >> 5;  // 8 k-parts x 64
    const int col = n0 + cg * 4;
    __shared__ float4 part[8][32];

    float4 acc = {0.f, 0.f, 0.f, 0.f};
    for (int k = kp * 64; k < kp * 64 + 64; ++k) {
        float g = catmean[(size_t)b * 512 + k];
        float4 w = *(const float4*)&Wm[(size_t)k * 1024 + col];
        acc.x += g * w.x;
        acc.y += g * w.y;
        acc.z += g * w.z;
        acc.w += g * w.w;
    }
    part[kp][cg] = acc;
    __syncthreads();
    if (tid < 32) {
        float4 s = part[0][tid];
#pragma unroll
        for (int z = 1; z < 8; ++z) {
            float4 p = part[z][tid];
            s.x += p.x; s.y += p.y; s.z += p.z; s.w += p.w;
        }
        float4 bb = *(const float4*)&bm[n0 + tid * 4];
        s.x += bb.x; s.y += bb.y; s.z += bb.z; s.w += bb.w;
        *(float4*)&gmeanv[(size_t)b * 1024 + n0 + tid * 4] = s;
    }
}

// ---------------- MFMA split-bf16 cat-GEMM + max pool ----------------
// 128x128 tile, 4 waves (64x64 each), 16x16x32 bf16 MFMA, 3-pass hi/lo emulation.
__global__ __launch_bounds__(256, 2) void gemm_cat_pool_kernel(
        const unsigned short* __restrict__ Ahp, const unsigned short* __restrict__ Alp,
        const unsigned short* __restrict__ Whp, const unsigned short* __restrict__ Wlp,
        float* __restrict__ pmax) {
    const int bid = blockIdx.x;  // 512
    const int xcd = bid & 7, pos = bid >> 3;
    const int nb = pos & 7, pb = (xcd << 3) | (pos >> 3);
    const int n0 = nb * 128, p0 = pb * 128;
    const int tid = threadIdx.x;
    const int wid = tid >> 6, lane = tid & 63;
    const int wm = (wid >> 1) * 64, wn = (wid & 1) * 64;

    // [buf][kb][chunk], kb-stride 132 chunks => 2112B (mod 128B = 64) => 2-way banks
    __shared__ uint4 sAh[2][4][132], sAl[2][4][132], sBh[2][4][132], sBl[2][4][132];
    __shared__ float sMax[2][128];

    f32x4 acc[4][4];
#pragma unroll
    for (int i = 0; i < 4; ++i)
#pragma unroll
        for (int j = 0; j < 4; ++j) acc[i][j] = {0.f, 0.f, 0.f, 0.f};

    const uint4* Ah4 = (const uint4*)Ahp;
    const uint4* Al4 = (const uint4*)Alp;
    const uint4* Wh4 = (const uint4*)Whp;
    const uint4* Wl4 = (const uint4*)Wlp;

    const int m0 = tid & 127, kb0 = tid >> 7;  // pair0; pair1 = (m0, kb0+2)
    uint4 rAh0, rAl0, rBh0, rBl0, rAh1, rAl1, rBh1, rBl1;

#define MP_LOAD(ck)                                                     \
    {                                                                   \
        int ksb = (ck) * 4;                                             \
        size_t a0 = (size_t)(ksb + kb0) * 8192 + p0 + m0;               \
        size_t a1 = (size_t)(ksb + kb0 + 2) * 8192 + p0 + m0;           \
        size_t b0 = (size_t)(ksb + kb0) * 1024 + n0 + m0;               \
        size_t b1 = (size_t)(ksb + kb0 + 2) * 1024 + n0 + m0;           \
        rAh0 = Ah4[a0]; rAl0 = Al4[a0];                                 \
        rAh1 = Ah4[a1]; rAl1 = Al4[a1];                                 \
        rBh0 = Wh4[b0]; rBl0 = Wl4[b0];                                 \
        rBh1 = Wh4[b1]; rBl1 = Wl4[b1];                                 \
    }

#define MP_WRITE(buf)                                                   \
    {                                                                   \
        sAh[buf][kb0][m0] = rAh0;  sAl[buf][kb0][m0] = rAl0;            \
        sAh[buf][kb0 + 2][m0] = rAh1;  sAl[buf][kb0 + 2][m0] = rAl1;    \
        sBh[buf][kb0][m0] = rBh0;  sBl[buf][kb0][m0] = rBl0;            \
        sBh[buf][kb0 + 2][m0] = rBh1;  sBl[buf][kb0 + 2][m0] = rBl1;    \
    }

    MP_LOAD(0);
    MP_WRITE(0);
    __syncthreads();

    const int fkb = lane >> 4, flm = lane & 15;

    for (int ck = 0; ck < 16; ++ck) {
        const int buf = ck & 1;
        if (ck < 15) MP_LOAD(ck + 1);

        bf16x8 fAh[4], fAl[4], fBh[4], fBl[4];
#pragma unroll
        for (int i = 0; i < 4; ++i) {
            fAh[i] = *(const bf16x8*)&sAh[buf][fkb][wm + i * 16 + flm];
            fAl[i] = *(const bf16x8*)&sAl[buf][fkb][wm + i * 16 + flm];
            fBh[i] = *(const bf16x8*)&sBh[buf][fkb][wn + i * 16 + flm];
            fBl[i] = *(const bf16x8*)&sBl[buf][fkb][wn + i * 16 + flm];
        }
#pragma unroll
        for (int i = 0; i < 4; ++i)
#pragma unroll
            for (int j = 0; j < 4; ++j) {
                acc[i][j] = __builtin_amdgcn_mfma_f32_16x16x32_bf16(fAh[i], fBh[j],
                                                                    acc[i][j], 0, 0, 0);
                acc[i][j] = __builtin_amdgcn_mfma_f32_16x16x32_bf16(fAh[i], fBl[j],
                                                                    acc[i][j], 0, 0, 0);
                acc[i][j] = __builtin_amdgcn_mfma_f32_16x16x32_bf16(fAl[i], fBh[j],
                                                                    acc[i][j], 0, 0, 0);
            }

        if (ck < 15) MP_WRITE(buf ^ 1);
        __syncthreads();
    }

    // max over rows: lane holds rows wm + i*16 + (lane>>4)*4 + r, col wn + j*16 + (lane&15)
    float cm[4];
#pragma unroll
    for (int j = 0; j < 4; ++j) {
        float m = acc[0][j][0];
#pragma unroll
        for (int i = 0; i < 4; ++i)
#pragma unroll
            for (int r = 0; r < 4; ++r) m = fmaxf(m, acc[i][j][r]);
        m = fmaxf(m, __shfl_xor(m, 16, 64));
        m = fmaxf(m, __shfl_xor(m, 32, 64));
        cm[j] = m;
    }
    if (lane < 16) {
#pragma unroll
        for (int j = 0; j < 4; ++j) sMax[wid >> 1][wn + j * 16 + lane] = cm[j];
    }
    __syncthreads();
    if (tid < 128)
        pmax[(size_t)pb * 1024 + n0 + tid] = fmaxf(sMax[0][tid], sMax[1][tid]);
#undef MP_LOAD
#undef MP_WRITE
}

// ---------------- fc_a: gm = [maxpool+bm, gmean]; ha = gm.Wa + ba ----------------
__global__ __launch_bounds__(256) void fc_a_kernel(const float* __restrict__ pmax,
                                                   const float* __restrict__ gmeanv,
                                                   const float* __restrict__ bm,
                                                   const float* __restrict__ Wa,
                                                   const float* __restrict__ ba,
                                                   float* __restrict__ ha) {
    const int b = blockIdx.y;
    const int n0 = blockIdx.x * 64;
    const int tid = threadIdx.x;
    __shared__ float gm[2048];
    __shared__ float4 part[16][16];

    for (int c = tid; c < 1024; c += 256) {
        float m = pmax[(size_t)(b * 8) * 1024 + c];
#pragma unroll
        for (int z = 1; z < 8; ++z) m = fmaxf(m, pmax[(size_t)(b * 8 + z) * 1024 + c]);
        gm[c] = m + bm[c];
        gm[1024 + c] = gmeanv[(size_t)b * 1024 + c];
    }
    __syncthreads();

    const int cg = tid & 15, kp = tid >> 4;
    const int co = n0 + cg * 4;
    float4 acc = {0.f, 0.f, 0.f, 0.f};
    const float* Wp = Wa + (size_t)(kp * 128) * 512 + co;
    const float* gp = gm + kp * 128;
#pragma unroll 8
    for (int k = 0; k < 128; ++k) {
        float g = gp[k];
        float4 w = *(const float4*)&Wp[(size_t)k * 512];
        acc.x += g * w.x;
        acc.y += g * w.y;
        acc.z += g * w.z;
        acc.w += g * w.w;
    }
    part[kp][cg] = acc;
    __syncthreads();
    if (tid < 16) {
        float4 s = part[0][tid];
#pragma unroll
        for (int z = 1; z < 16; ++z) {
            float4 p = part[z][tid];
            s.x += p.x; s.y += p.y; s.z += p.z; s.w += p.w;
        }
        float4 bb = *(const float4*)&ba[n0 + tid * 4];
        s.x += bb.x; s.y += bb.y; s.z += bb.z; s.w += bb.w;
        *(float4*)&ha[(size_t)b * 512 + n0 + tid * 4] = s;
    }
}

__global__ __launch_bounds__(256) void bn_leaky_kernel(float* __restrict__ h,
                                                       const float* __restrict__ g,
                                                       const float* __restrict__ be,
                                                       int ncol) {
    int co = blockIdx.x * 256 + threadIdx.x;
    if (co >= ncol) return;
    float mu = 0.f;
    for (int b = 0; b < NB; ++b) mu += h[b * ncol + co];
    mu *= 0.125f;
    float var = 0.f;
    for (int b = 0; b < NB; ++b) {
        float d = h[b * ncol + co] - mu;
        var += d * d;
    }
    var *= 0.125f;
    float inv = 1.0f / sqrtf(var + 1e-5f);
    for (int b = 0; b < NB; ++b) {
        float v = (h[b * ncol + co] - mu) * inv * g[co] + be[co];
        h[b * ncol + co] = v >= 0.f ? v : 0.2f * v;
    }
}

// ---------------- fc_b: [8,512]x[512,256], K-split 16 ----------------
__global__ __launch_bounds__(256) void fc_b_kernel(const float* __restrict__ ha,
                                                   const float* __restrict__ Wb,
                                                   const float* __restrict__ bb,
                                                   float* __restrict__ hb) {
    const int b = blockIdx.y;
    const int n0 = blockIdx.x * 64;
    const int tid = threadIdx.x;
    __shared__ float sh[512];
    __shared__ float4 part[16][16];

    for (int c = tid; c < 512; c += 256) sh[c] = ha[(size_t)b * 512 + c];
    __syncthreads();

    const int cg = tid & 15, kp = tid >> 4;
    const int co = n0 + cg * 4;
    float4 acc = {0.f, 0.f, 0.f, 0.f};
#pragma unroll 8
    for (int k = 0; k < 32; ++k) {
        float g = sh[kp * 32 + k];
        float4 w = *(const float4*)&Wb[(size_t)(kp * 32 + k) * 256 + co];
        acc.x += g * w.x;
        acc.y += g * w.y;
        acc.z += g * w.z;
        acc.w += g * w.w;
    }
    part[kp][cg] = acc;
    __syncthreads();
    if (tid < 16) {
        float4 s = part[0][tid];
#pragma unroll
        for (int z = 1; z < 16; ++z) {
            float4 p = part[z][tid];
            s.x += p.x; s.y += p.y; s.z += p.z; s.w += p.w;
        }
        float4 bv = *(const float4*)&bb[n0 + tid * 4];
        s.x += bv.x; s.y += bv.y; s.z += bv.z; s.w += bv.w;
        *(float4*)&hb[(size_t)b * 256 + n0 + tid * 4] = s;
    }
}

__global__ __launch_bounds__(256) void fc_c_kernel(const float* __restrict__ hb,
                                                   const float* __restrict__ Wc,
                                                   const float* __restrict__ bc,
                                                   float* __restrict__ outp) {
    int t = blockIdx.x * 256 + threadIdx.x;  // 8*40
    if (t >= 8 * 40) return;
    int b = t / 40, o = t - b * 40;
    float s = bc[o];
    for (int c = 0; c < 256; ++c) s += hb[b * 256 + c] * Wc[c * 40 + o];
    outp[t] = s;
}

extern "C" void kernel_launch(void* const* d_in, const int* in_sizes, int n_in,
                              void* d_out, int out_size, void* d_ws, size_t ws_size,
                              hipStream_t stream) {
    const float* pos = (const float*)d_in[0];
    const float* W1 = (const float*)d_in[2];
    const float* b1 = (const float*)d_in[3];
    const float* W2 = (const float*)d_in[4];
    const float* b2 = (const float*)d_in[5];
    const float* W3 = (const float*)d_in[6];
    const float* b3 = (const float*)d_in[7];
    const float* W4 = (const float*)d_in[8];
    const float* b4 = (const float*)d_in[9];
    const float* Wm = (const float*)d_in[10];
    const float* bm = (const float*)d_in[11];
    const float* Wa = (const float*)d_in[12];
    const float* ba = (const float*)d_in[13];
    const float* ga = (const float*)d_in[14];
    const float* bea = (const float*)d_in[15];
    const float* Wb = (const float*)d_in[16];
    const float* bb = (const float*)d_in[17];
    const float* gb = (const float*)d_in[18];
    const float* beb = (const float*)d_in[19];
    const float* Wc = (const float*)d_in[20];
    const float* bc = (const float*)d_in[21];
    float* out = (float*)d_out;

    char* ws = (char*)d_ws;
    size_t off = 0;
    auto alloc = [&](size_t bytes) {
        void* p = ws + off;
        off += (bytes + 255) & ~(size_t)255;
        return p;
    };
    int* idx = (int*)alloc((size_t)NPTS * KNN * 4);
    float* x1 = (float*)alloc((size_t)NPTS * 64 * 4);
    float* x2 = (float*)alloc((size_t)NPTS * 64 * 4);
    float* x3 = (float*)alloc((size_t)NPTS * 128 * 4);
    float* x4 = (float*)alloc((size_t)NPTS * 256 * 4);
    float* scratch = (float*)alloc((size_t)NPTS * 1024 * 4);  // Dm / AB / bf16 panels
    float* pmax = (float*)alloc((size_t)64 * 1024 * 4);
    float* catmean = (float*)alloc(NB * 512 * 4);
    float* gmeanv = (float*)alloc(NB * 1024 * 4);
    float* ha = (float*)alloc(NB * 512 * 4);
    float* hb = (float*)alloc(NB * 256 * 4);
    (void)ws_size;

    float* Dm = scratch;
    float* AB = scratch;
    // bf16 panels alias scratch (live only after layer-4 gather, before fc_a)
    char* sc = (char*)scratch;
    unsigned short* Ach = (unsigned short*)sc;                          // 8.39 MB
    unsigned short* Acl = (unsigned short*)(sc + 8388608);              // 8.39 MB
    unsigned short* Wth = (unsigned short*)(sc + 16777216);             // 1.05 MB
    unsigned short* Wtl = (unsigned short*)(sc + 16777216 + 1048576);   // 1.05 MB

    dim3 dgrid128(8, 8, 8);

    // layer 1 (C=3 -> 64)
    dist3_kernel<<<dim3(16, 16, 8), 256, 0, stream>>>(pos, Dm);
    topk_kernel<<<NPTS / 4, 256, 0, stream>>>(Dm, idx);
    edge_gemm_kernel<3, 64><<<dim3(1, 128), 256, 0, stream>>>(pos, W1, b1, AB);
    gather_max_kernel<64><<<NPTS / 16, 256, 0, stream>>>(AB, idx, x1);

    // layer 2 (64 -> 64)
    dist128_kernel<64><<<dgrid128, 256, 0, stream>>>(x1, Dm);
    topk_kernel<<<NPTS / 4, 256, 0, stream>>>(Dm, idx);
    edge_gemm_kernel<64, 64><<<dim3(1, 128), 256, 0, stream>>>(x1, W2, b2, AB);
    gather_max_kernel<64><<<NPTS / 16, 256, 0, stream>>>(AB, idx, x2);

    // layer 3 (64 -> 128)
    dist128_kernel<64><<<dgrid128, 256, 0, stream>>>(x2, Dm);
    topk_kernel<<<NPTS / 4, 256, 0, stream>>>(Dm, idx);
    edge_gemm_kernel<64, 128><<<dim3(2, 128), 256, 0, stream>>>(x2, W3, b3, AB);
    gather_max_kernel<128><<<NPTS / 8, 256, 0, stream>>>(AB, idx, x3);

    // layer 4 (128 -> 256)
    dist128_kernel<128><<<dgrid128, 256, 0, stream>>>(x3, Dm);
    topk_kernel<<<NPTS / 4, 256, 0, stream>>>(Dm, idx);
    edge_gemm_kernel<128, 256><<<dim3(4, 128), 256, 0, stream>>>(x3, W4, b4, AB);
    gather_max_kernel<256><<<NPTS / 4, 256, 0, stream>>>(AB, idx, x4);

    // mean path (commutes with linear map)
    catmean_kernel<<<dim3(4, NB), 256, 0, stream>>>(x1, x2, x3, x4, catmean);
    gmean_kernel<<<dim3(8, NB), 256, 0, stream>>>(catmean, Wm, bm, gmeanv);

    // bf16 split conversion (panels overwrite scratch — AB no longer needed)
    convert_cat_kernel<<<2048, 256, 0, stream>>>(x1, x2, x3, x4, Ach, Acl);
    convert_w_kernel<<<256, 256, 0, stream>>>(Wm, Wth, Wtl);

    // MFMA cat-GEMM + max pool (bias deferred to fc_a)
    gemm_cat_pool_kernel<<<512, 256, 0, stream>>>(Ach, Acl, Wth, Wtl, pmax);

    // head
    fc_a_kernel<<<dim3(8, NB), 256, 0, stream>>>(pmax, gmeanv, bm, Wa, ba, ha);
    bn_leaky_kernel<<<2, 256, 0, stream>>>(ha, ga, bea, 512);
    fc_b_kernel<<<dim3(4, NB), 256, 0, stream>>>(ha, Wb, bb, hb);
    bn_leaky_kernel<<<1, 256, 0, stream>>>(hb, gb, beb, 256);
    fc_c_kernel<<<2, 256, 0, stream>>>(hb, Wc, bc, out);
}